// Round 1
// 3668.440 us; speedup vs baseline: 1.1041x; 1.1041x over previous
//
#include <hip/hip_runtime.h>
#include <hip/hip_bf16.h>
#include <hip/hip_fp16.h>

// BiLSTM encoder (L=400) + coverage-attention LSTM decoder (T-1=99) + V=50000 softmax.
// B=16, E=128, H=256, 4H=1024, 2H=512, 3H=768.
//
// Round-3 change: fence-free grid barriers in both persistent kernels.
//  - Previous: __threadfence() (buffer_wbl2/buffer_inv sc1 = full-L2 maintenance)
//    twice per recurrence step -> ~4.5 us/step, pure sync latency.
//  - Now: all cross-WG data (h hi/lo planes, p_pub, q_pub) moves via coherent
//    sc0 sc1 loads/stores (coherence point = L3), relaxed agent atomics for the
//    counter, explicit s_waitcnt vmcnt(0) drains. No cache flushes at all.
//  - Coherent 16B loads are batch-issued inline asm + single waitcnt +
//    sched_barrier(0) (guide rule #18), all array indices static (rule #20).

#define BB 16
#define LL 400
#define TD 99
#define G4 1024
#define H2 512
#define H3 768
#define VV 50000

typedef __attribute__((ext_vector_type(8))) short bf16x8_t;
typedef __attribute__((ext_vector_type(8))) _Float16 f16x8_t;
typedef __attribute__((ext_vector_type(4))) float f32x4_t;
typedef unsigned short ushort_t;

static constexpr size_t OFF_XF   = 0;            // 6,553,600  (aliased by encT f16 after encoder)
static constexpr size_t OFF_XB   = 6553600;      // 6,553,600
static constexpr size_t OFF_XD   = 13107200;     // 1,622,016
static constexpr size_t OFF_ENC  = 14729216;     // 3,276,800
static constexpr size_t OFF_CAT  = 18006016;     // 1,216,512
static constexpr size_t OFF_ZBF  = 19222528;     // 786,432 floats = ushort[2048*768]
static constexpr size_t OFF_ATTN = 20008960;     // 372,736 floats = half[16*112*416]
static constexpr size_t OFF_VWH  = 20381696;     // 6400
static constexpr size_t OFF_VWS  = 20388096;     // 256
static constexpr size_t OFF_VWC  = 20388352;     // 512
static constexpr size_t OFF_VWHW = 20388864;     // 512
static constexpr size_t OFF_C0   = 20389376;     // 16
static constexpr size_t OFF_HENC = 20389392;     // 16,384 floats = ushort[2][2][2][4096]
static constexpr size_t OFF_HDEC = 20405776;     // 8,192 floats = ushort[2][2][4096]
static constexpr size_t OFF_PPUB = 20413968;     // 512
static constexpr size_t OFF_QPUB = 20414480;     // 32
static constexpr size_t OFF_CNT  = 20414512;     // 64 (u32 counters: +0 enc dir0, +16 enc dir1, +32 dec)
static constexpr size_t OFF_CVL  = 20414576;     // 16
static constexpr size_t OFF_END  = 20414592;     // ~81.7 MB
static constexpr size_t ZERO_N   = OFF_END - OFF_HENC;  // 25,200

__device__ __forceinline__ ushort_t f2bf(float x) {
    unsigned u = __float_as_uint(x);
    unsigned r = u + 0x7FFFu + ((u >> 16) & 1u);
    return (ushort_t)(r >> 16);
}
__device__ __forceinline__ float bf2f(ushort_t h) {
    return __uint_as_float(((unsigned)h) << 16);
}
__device__ __forceinline__ float wred_sum(float v) {
#pragma unroll
    for (int o = 32; o; o >>= 1) v += __shfl_xor(v, o);
    return v;
}
__device__ __forceinline__ float wred_max(float v) {
#pragma unroll
    for (int o = 32; o; o >>= 1) v = fmaxf(v, __shfl_xor(v, o));
    return v;
}
__device__ __forceinline__ float sigf(float x) { return 1.f / (1.f + expf(-x)); }

// Coherent (L1/L2-bypassing) paired 16B loads of hi/lo h-fragment planes.
// OFFS is a literal byte offset string (kk*64). Results NOT ready until CCWAIT.
#define CCLOAD2(ii, OFFS)                                                          \
    asm volatile("global_load_dwordx4 %0, %2, off offset:" OFFS " sc0 sc1\n\t"     \
                 "global_load_dwordx4 %1, %3, off offset:" OFFS " sc0 sc1"         \
                 : "=&v"(ah[ii]), "=&v"(al[ii])                                    \
                 : "v"(pa), "v"(pb)                                                \
                 : "memory")

#define CCLOAD_ALL()                                                               \
    do {                                                                           \
        CCLOAD2(0, "0");   CCLOAD2(1, "64");  CCLOAD2(2, "128"); CCLOAD2(3, "192");\
        CCLOAD2(4, "256"); CCLOAD2(5, "320"); CCLOAD2(6, "384"); CCLOAD2(7, "448");\
    } while (0)

#define CCWAIT()                                                                   \
    do {                                                                           \
        asm volatile("s_waitcnt vmcnt(0)" ::: "memory");                           \
        __builtin_amdgcn_sched_barrier(0);                                         \
    } while (0)

// ---------------- init: zero state region ----------------
__global__ void k_init(float* __restrict__ p, int n) {
    for (int i = blockIdx.x * blockDim.x + threadIdx.x; i < n; i += gridDim.x * blockDim.x)
        p[i] = 0.0f;
}

// ---------------- precompute v-folded attention vectors ----------------
__global__ void k_precomp(const float* __restrict__ v, const float* __restrict__ Ws_w,
                          const float* __restrict__ Wc_w, const float* __restrict__ Wh_w,
                          const float* __restrict__ Wh_b, const float* __restrict__ Ws_b,
                          const float* __restrict__ Wc_b, const float* __restrict__ v_b,
                          float* __restrict__ vWs, float* __restrict__ vWc,
                          float* __restrict__ vWhw, float* __restrict__ c0) {
    int tid = threadIdx.x;
    {
        float a = 0.f;
        for (int j = 0; j < 256; ++j) a += v[j] * Ws_w[j * 256 + tid];
        vWs[tid] = a;
    }
    for (int k = tid; k < 400; k += 256) {
        float a = 0.f;
        for (int j = 0; j < 256; ++j) a += v[j] * Wc_w[j * 400 + k];
        vWc[k] = a;
    }
    for (int k = tid; k < 512; k += 256) {
        float a = 0.f;
        for (int j = 0; j < 256; ++j) a += v[j] * Wh_w[j * 512 + k];
        vWhw[k] = a;
    }
    if (tid == 0) {
        float a = 0.f;
        for (int j = 0; j < 256; ++j) a += v[j] * (Wh_b[j] + Ws_b[j] + Wc_b[j]);
        c0[0] = a + v_b[0];
    }
}

// ---------------- gather x-projection GEMM (split-bf16, 3 MFMA) ----------------
// C[M,1024] = embed[tok(m)] @ Wih.T + bias ; tok(m) = toks[(m&15)*S + (m>>4)]
__global__ __launch_bounds__(256) void k_xproj(
    const float* __restrict__ emb, const int* __restrict__ toks, int tokStride,
    const float* __restrict__ Wih, const float* __restrict__ bias,
    float* __restrict__ C, int M) {
    __shared__ __attribute__((aligned(16))) ushort_t Ah[64 * 32], Al[64 * 32];
    __shared__ __attribute__((aligned(16))) ushort_t Bh[64 * 32], Bl[64 * 32];
    int tid = threadIdx.x;
    int m0 = blockIdx.y * 64, n0 = blockIdx.x * 64;
    int lrow = tid >> 2, lc = (tid & 3) * 8;
    int g = tid >> 6, lane = tid & 63, lm = lane & 15, quad = lane >> 4;
    f32x4_t acc[4];
#pragma unroll
    for (int i = 0; i < 4; ++i) acc[i] = (f32x4_t){0.f, 0.f, 0.f, 0.f};
    int mr = m0 + lrow;
    int l = mr >> 4, bb2 = mr & 15;
    int tok = (mr < M) ? toks[bb2 * tokStride + l] : 0;
    const float* arow = emb + (size_t)tok * 128;
    const float* brow = Wih + (size_t)(n0 + lrow) * 128;
    for (int k0 = 0; k0 < 128; k0 += 32) {
        float av[8], bv[8];
        *(float4*)(av) = *(const float4*)(arow + k0 + lc);
        *(float4*)(av + 4) = *(const float4*)(arow + k0 + lc + 4);
        *(float4*)(bv) = *(const float4*)(brow + k0 + lc);
        *(float4*)(bv + 4) = *(const float4*)(brow + k0 + lc + 4);
        __syncthreads();
#pragma unroll
        for (int j = 0; j < 8; ++j) {
            ushort_t h = f2bf(av[j]);
            Ah[lrow * 32 + lc + j] = h;
            Al[lrow * 32 + lc + j] = f2bf(av[j] - bf2f(h));
            ushort_t h2 = f2bf(bv[j]);
            Bh[lrow * 32 + lc + j] = h2;
            Bl[lrow * 32 + lc + j] = f2bf(bv[j] - bf2f(h2));
        }
        __syncthreads();
        bf16x8_t ah = *(const bf16x8_t*)(Ah + (g * 16 + lm) * 32 + quad * 8);
        bf16x8_t al = *(const bf16x8_t*)(Al + (g * 16 + lm) * 32 + quad * 8);
#pragma unroll
        for (int ns = 0; ns < 4; ++ns) {
            bf16x8_t bh = *(const bf16x8_t*)(Bh + (ns * 16 + lm) * 32 + quad * 8);
            bf16x8_t bl = *(const bf16x8_t*)(Bl + (ns * 16 + lm) * 32 + quad * 8);
            acc[ns] = __builtin_amdgcn_mfma_f32_16x16x32_bf16(ah, bh, acc[ns], 0, 0, 0);
            acc[ns] = __builtin_amdgcn_mfma_f32_16x16x32_bf16(ah, bl, acc[ns], 0, 0, 0);
            acc[ns] = __builtin_amdgcn_mfma_f32_16x16x32_bf16(al, bh, acc[ns], 0, 0, 0);
        }
    }
#pragma unroll
    for (int ns = 0; ns < 4; ++ns) {
        int n = n0 + ns * 16 + lm;
        float bb = bias[n];
#pragma unroll
        for (int r2 = 0; r2 < 4; ++r2) {
            int mm = m0 + g * 16 + quad * 4 + r2;
            if (mm < M) C[(size_t)mm * 1024 + n] = acc[ns][r2] + bb;
        }
    }
}

// ---------------- persistent encoder: 32 WGs = 2 dirs x 16 k-slices ----------------
__global__ __launch_bounds__(256) void k_enc_pers(
    const float* __restrict__ Xf, const float* __restrict__ Xb,
    const float* __restrict__ Whh_f, const float* __restrict__ Whh_b,
    ushort_t* __restrict__ hbuf, unsigned* __restrict__ cnts, float* __restrict__ enc) {
    __shared__ float pre[1024];
    int bx = blockIdx.x;
    int q = bx >> 3, r = bx & 7;
    int dir = r >> 2;
    int w = q * 4 + (r & 3);            // XCD-split: each dir lives on 4 XCDs
    const float* Whh = dir ? Whh_b : Whh_f;
    const float* X = dir ? Xb : Xf;
    unsigned* cnt = cnts + dir * 16;
    ushort_t* hb = hbuf + dir * 16384;  // [par][plane][4096]
    int tid = threadIdx.x;
    int g = tid >> 6, lane = tid & 63, lm = lane & 15, quad = lane >> 4;
    int gbase = 256 * g + 16 * w;
    bf16x8_t Bh[8], Bl[8];
    {
        const float* wr = Whh + (size_t)(gbase + lm) * 256;
#pragma unroll
        for (int kk = 0; kk < 8; ++kk) {
            union { bf16x8_t v; ushort_t u[8]; } hh, ll;
#pragma unroll
            for (int j = 0; j < 8; ++j) {
                float x = wr[kk * 32 + quad * 8 + j];
                ushort_t hi = f2bf(x);
                hh.u[j] = hi;
                ll.u[j] = f2bf(x - bf2f(hi));
            }
            Bh[kk] = hh.v;
            Bl[kk] = ll.v;
        }
    }
    int m = tid >> 4, kk16 = tid & 15;
    int k = w * 16 + kk16;
    // coherent h-exchange pointers (hi/lo planes, par 0/1)
    const ushort_t* paA = hb + lm * 256 + quad * 8;    // par0 hi
    const ushort_t* pbA = paA + 4096;                  // par0 lo
    const ushort_t* paB = paA + 8192;                  // par1 hi
    const ushort_t* pbB = paA + 12288;                 // par1 lo
    ushort_t* soA = hb + 8192 + m * 256 + k;           // out when par=0 -> buf1
    ushort_t* soB = hb + m * 256 + k;                  // out when par=1 -> buf0
    float c = 0.f;
    int l0 = dir ? 399 : 0;
    const float* Xr0 = X + (size_t)(l0 * 16 + m) * 1024;
    float x0 = Xr0[k], x1 = Xr0[256 + k], x2 = Xr0[512 + k], x3 = Xr0[768 + k];
    for (int t = 0; t < 400; ++t) {
        int par = t & 1;
        const ushort_t* pa = par ? paB : paA;
        const ushort_t* pb = par ? pbB : pbA;
        bf16x8_t ah[8], al[8];
        CCLOAD_ALL();
        CCWAIT();
        f32x4_t acc = (f32x4_t){0.f, 0.f, 0.f, 0.f};
#pragma unroll
        for (int kk = 0; kk < 8; ++kk) {
            acc = __builtin_amdgcn_mfma_f32_16x16x32_bf16(ah[kk], Bh[kk], acc, 0, 0, 0);
            acc = __builtin_amdgcn_mfma_f32_16x16x32_bf16(ah[kk], Bl[kk], acc, 0, 0, 0);
            acc = __builtin_amdgcn_mfma_f32_16x16x32_bf16(al[kk], Bh[kk], acc, 0, 0, 0);
        }
#pragma unroll
        for (int r2 = 0; r2 < 4; ++r2) pre[g * 256 + (quad * 4 + r2) * 16 + lm] = acc[r2];
        __syncthreads();
        float gi = pre[tid] + x0;
        float gf = pre[256 + tid] + x1;
        float gg = pre[512 + tid] + x2;
        float go = pre[768 + tid] + x3;
        int l = dir ? (399 - t) : t;
        if (t < 399) {  // prefetch next step's x
            int ln = dir ? (398 - t) : (t + 1);
            const float* Xr = X + (size_t)(ln * 16 + m) * 1024;
            x0 = Xr[k]; x1 = Xr[256 + k]; x2 = Xr[512 + k]; x3 = Xr[768 + k];
        }
        c = sigf(gf) * c + sigf(gi) * tanhf(gg);
        float h = sigf(go) * tanhf(c);
        enc[((size_t)m * 400 + l) * 512 + dir * 256 + k] = h;
        ushort_t hh = f2bf(h);
        unsigned hhi32 = hh;
        unsigned hlo32 = f2bf(h - bf2f(hh));
        ushort_t* so = par ? soB : soA;
        asm volatile("global_store_short %0, %2, off sc0 sc1\n\t"
                     "global_store_short %1, %3, off sc0 sc1"
                     :: "v"(so), "v"(so + 4096), "v"(hhi32), "v"(hlo32) : "memory");
        // drain own coherent stores before signaling (compiler can't track asm stores)
        asm volatile("s_waitcnt vmcnt(0)" ::: "memory");
        __syncthreads();   // all WG lanes drained
        if (tid == 0) {
            __hip_atomic_fetch_add(cnt, 1u, __ATOMIC_RELAXED, __HIP_MEMORY_SCOPE_AGENT);
            unsigned tgt = (unsigned)(t + 1) * 16u;
            while (__hip_atomic_load(cnt, __ATOMIC_RELAXED, __HIP_MEMORY_SCOPE_AGENT) < tgt)
                __builtin_amdgcn_s_sleep(2);
        }
        __syncthreads();
    }
}

// ---------------- vWh[b*L+l] = vWhw . enc[b,l,:] ----------------
__global__ void k_vwh(const float* __restrict__ enc, const float* __restrict__ vWhw,
                      float* __restrict__ vWh) {
    int rr = blockIdx.x * 256 + threadIdx.x;
    const float* row = enc + (size_t)rr * H2;
    float acc = 0.f;
#pragma unroll 4
    for (int k = 0; k < H2; k += 4) {
        float4 e = *(const float4*)(row + k);
        float4 wv = *(const float4*)(vWhw + k);
        acc += e.x * wv.x + e.y * wv.y + e.z * wv.z + e.w * wv.w;
    }
    vWh[rr] = acc;
}

// ---------------- transpose enc -> encT f16 [b][j][l(416, zero-padded)] ----------------
__global__ __launch_bounds__(256) void k_transpose(const float* __restrict__ enc,
                                                   __half* __restrict__ encT) {
    __shared__ float tb[64][65];
    int lt = blockIdx.x, jt = blockIdx.y, b = blockIdx.z;
    int l0 = lt * 64, j0 = jt * 64;
    int tid = threadIdx.x;
    for (int i = tid; i < 4096; i += 256) {
        int li = i >> 6, jj = i & 63;
        int l = l0 + li;
        tb[jj][li] = (l < 400) ? enc[((size_t)b * 400 + l) * 512 + j0 + jj] : 0.f;
    }
    __syncthreads();
    for (int i = tid; i < 4096; i += 256) {
        int jj = i >> 6, li = i & 63;
        int l = l0 + li;
        if (l < 416) encT[((size_t)b * 512 + j0 + jj) * 416 + l] = __float2half(tb[jj][li]);
    }
}

// ---------------- persistent decoder: 16 WGs (k-slice for LSTM, batch for attention) ----
__global__ __launch_bounds__(256) void k_dec_pers(
    const float* __restrict__ Xd, const float* __restrict__ Whh_d,
    ushort_t* __restrict__ hbuf, unsigned* __restrict__ cnt,
    const float* __restrict__ vWh, const float* __restrict__ vWs,
    const float* __restrict__ vWc, const float* __restrict__ c0g,
    float* __restrict__ p_pub, float* __restrict__ q_pub, float* __restrict__ cat,
    __half* __restrict__ attn_g, float* __restrict__ cvl) {
    __shared__ float pre[1024];
    __shared__ float covL[400];
    __shared__ float vred[256];
    __shared__ float psh[256];
    __shared__ float vswcS[16];
    __shared__ float rr[8];
    int w = blockIdx.x;
    int b = w;
    int tid = threadIdx.x;
    int g = tid >> 6, lane = tid & 63, lm = lane & 15, quad = lane >> 4;
    int gbase = 256 * g + 16 * w;
    bf16x8_t Bh[8], Bl[8];
    {
        const float* wr = Whh_d + (size_t)(gbase + lm) * 256;
#pragma unroll
        for (int kk = 0; kk < 8; ++kk) {
            union { bf16x8_t v; ushort_t u[8]; } hh, ll;
#pragma unroll
            for (int j = 0; j < 8; ++j) {
                float x = wr[kk * 32 + quad * 8 + j];
                ushort_t hi = f2bf(x);
                hh.u[j] = hi;
                ll.u[j] = f2bf(x - bf2f(hi));
            }
            Bh[kk] = hh.v;
            Bl[kk] = ll.v;
        }
    }
    int m = tid >> 4, kk16 = tid & 15;
    int k = w * 16 + kk16;
    const ushort_t* paA = hbuf + lm * 256 + quad * 8;  // par0 hi
    const ushort_t* pbA = paA + 4096;                  // par0 lo
    const ushort_t* paB = paA + 8192;                  // par1 hi
    const ushort_t* pbB = paA + 12288;                 // par1 lo
    ushort_t* soA = hbuf + 8192 + m * 256 + k;
    ushort_t* soB = hbuf + m * 256 + k;
    float c = 0.f, cl_acc = 0.f;
    for (int i = tid; i < 400; i += 256) covL[i] = 0.f;
    float c0v = c0g[0];
    float vwsk = vWs[k];
    const float* Xr0 = Xd + (size_t)m * 1024;
    float x0 = Xr0[k], x1 = Xr0[256 + k], x2 = Xr0[512 + k], x3 = Xr0[768 + k];
    __syncthreads();
    for (int t = 0; t < TD; ++t) {
        int par = t & 1;
        // ---- issue coherent h loads, overlap q = vWc . cov while they fly ----
        const ushort_t* pa = par ? paB : paA;
        const ushort_t* pb = par ? pbB : pbA;
        bf16x8_t ah[8], al[8];
        CCLOAD_ALL();
        float qv = 0.f;
        for (int i = tid; i < 400; i += 256) qv += vWc[i] * covL[i];
        qv = wred_sum(qv);
        CCWAIT();
        // ---- LSTM MFMA ----
        f32x4_t acc = (f32x4_t){0.f, 0.f, 0.f, 0.f};
#pragma unroll
        for (int kk = 0; kk < 8; ++kk) {
            acc = __builtin_amdgcn_mfma_f32_16x16x32_bf16(ah[kk], Bh[kk], acc, 0, 0, 0);
            acc = __builtin_amdgcn_mfma_f32_16x16x32_bf16(ah[kk], Bl[kk], acc, 0, 0, 0);
            acc = __builtin_amdgcn_mfma_f32_16x16x32_bf16(al[kk], Bh[kk], acc, 0, 0, 0);
        }
#pragma unroll
        for (int r2 = 0; r2 < 4; ++r2) pre[g * 256 + (quad * 4 + r2) * 16 + lm] = acc[r2];
        if (lane == 0) rr[g] = qv;
        __syncthreads();
        // ---- activations ----
        float gi = pre[tid] + x0;
        float gf = pre[256 + tid] + x1;
        float gg = pre[512 + tid] + x2;
        float go = pre[768 + tid] + x3;
        if (t < TD - 1) {
            const float* Xr = Xd + (size_t)((t + 1) * 16 + m) * 1024;
            x0 = Xr[k]; x1 = Xr[256 + k]; x2 = Xr[512 + k]; x3 = Xr[768 + k];
        }
        c = sigf(gf) * c + sigf(gi) * tanhf(gg);
        float h = sigf(go) * tanhf(c);
        cat[((size_t)t * 16 + m) * 768 + k] = h;
        ushort_t hh = f2bf(h);
        unsigned hhi32 = hh;
        unsigned hlo32 = f2bf(h - bf2f(hh));
        ushort_t* so = par ? soB : soA;
        asm volatile("global_store_short %0, %2, off sc0 sc1\n\t"
                     "global_store_short %1, %3, off sc0 sc1"
                     :: "v"(so), "v"(so + 4096), "v"(hhi32), "v"(hlo32) : "memory");
        psh[tid] = vwsk * h;
        if (tid == 0)
            __hip_atomic_store(&q_pub[par * 16 + b], rr[0] + rr[1] + rr[2] + rr[3],
                               __ATOMIC_RELAXED, __HIP_MEMORY_SCOPE_AGENT);
        __syncthreads();
        if (tid < 16) {
            float s = 0.f;
#pragma unroll
            for (int j = 0; j < 16; ++j) s += psh[tid * 16 + j];
            __hip_atomic_store(&p_pub[par * 256 + w * 16 + tid], s,
                               __ATOMIC_RELAXED, __HIP_MEMORY_SCOPE_AGENT);
        }
        // drain coherent stores (asm h stores + builtin atomics) before signaling
        asm volatile("s_waitcnt vmcnt(0)" ::: "memory");
        __syncthreads();
        // ---- grid barrier (fence-free) ----
        if (tid == 0) {
            __hip_atomic_fetch_add(cnt, 1u, __ATOMIC_RELAXED, __HIP_MEMORY_SCOPE_AGENT);
            unsigned tgt = (unsigned)(t + 1) * 16u;
            while (__hip_atomic_load(cnt, __ATOMIC_RELAXED, __HIP_MEMORY_SCOPE_AGENT) < tgt)
                __builtin_amdgcn_s_sleep(2);
        }
        __syncthreads();
        // ---- attention (WG = batch b) ----
        vred[tid] = __hip_atomic_load(&p_pub[par * 256 + tid], __ATOMIC_RELAXED,
                                      __HIP_MEMORY_SCOPE_AGENT);
        __syncthreads();
        if (tid < 128) vred[tid] += vred[tid + 128];
        __syncthreads();
        if (tid < 64) vred[tid] += vred[tid + 64];
        __syncthreads();
        if (tid < 32) vred[tid] += vred[tid + 32];
        __syncthreads();
        if (tid < 16)
            vswcS[tid] = vred[tid] + vred[tid + 16] +
                         __hip_atomic_load(&q_pub[par * 16 + tid], __ATOMIC_RELAXED,
                                           __HIP_MEMORY_SCOPE_AGENT);
        __syncthreads();
        bool has2 = tid < 144;
        float vs = vswcS[tid & 15] + c0v;  // (b*400+l)%16 == l%16 == tid%16 for both l=tid, tid+256
        float lg1 = vWh[b * 400 + tid] + vs;
        float lg2 = has2 ? (vWh[b * 400 + 256 + tid] + vs) : -1e30f;
        float mx = wred_max(fmaxf(lg1, lg2));
        if (lane == 0) rr[g] = mx;
        __syncthreads();
        float M = fmaxf(fmaxf(rr[0], rr[1]), fmaxf(rr[2], rr[3]));
        float e1 = expf(lg1 - M);
        float e2 = has2 ? expf(lg2 - M) : 0.f;
        float sv = wred_sum(e1 + e2);
        if (lane == 0) rr[4 + g] = sv;
        __syncthreads();
        float inv = 1.f / (rr[4] + rr[5] + rr[6] + rr[7]);
        float a1 = e1 * inv, a2 = e2 * inv;
        float cv1 = covL[tid];
        float cl = fminf(a1, cv1);
        covL[tid] = cv1 + a1;
        __half* arow = attn_g + ((size_t)b * 112 + t) * 416;
        arow[tid] = __float2half(a1);
        if (has2) {
            float cv2 = covL[tid + 256];
            cl += fminf(a2, cv2);
            covL[tid + 256] = cv2 + a2;
            arow[256 + tid] = __float2half(a2);
        }
        cl = wred_sum(cl);
        __syncthreads();
        if (lane == 0) rr[g] = cl;
        __syncthreads();
        if (tid == 0) cl_acc += rr[0] + rr[1] + rr[2] + rr[3];
        __syncthreads();   // covL updates visible before next step's q
    }
    if (tid == 0) atomicAdd(cvl, cl_acc);
}

// ---------------- batched context GEMM: cat[t*16+b][256:768] = attn @ enc ----------------
__global__ __launch_bounds__(256) void k_ctx_gemm(const __half* __restrict__ attn_g,
                                                  const __half* __restrict__ encT,
                                                  float* __restrict__ cat) {
    int jt = blockIdx.x, b = blockIdx.y;
    int tid = threadIdx.x, v = tid >> 6, lane = tid & 63, lm = lane & 15, quad = lane >> 4;
    f32x4_t acc[7];
#pragma unroll
    for (int i = 0; i < 7; ++i) acc[i] = (f32x4_t){0.f, 0.f, 0.f, 0.f};
    int j = jt * 64 + v * 16 + lm;
    const _Float16* brow = (const _Float16*)(encT + ((size_t)b * 512 + j) * 416);
    const _Float16* abase = (const _Float16*)(attn_g + (size_t)b * 112 * 416);
    for (int k0 = 0; k0 < 416; k0 += 32) {
        f16x8_t bf = *(const f16x8_t*)(brow + k0 + quad * 8);
#pragma unroll
        for (int mt = 0; mt < 7; ++mt) {
            f16x8_t af = *(const f16x8_t*)(abase + (size_t)(mt * 16 + lm) * 416 + k0 + quad * 8);
            acc[mt] = __builtin_amdgcn_mfma_f32_16x16x32_f16(af, bf, acc[mt], 0, 0, 0);
        }
    }
#pragma unroll
    for (int mt = 0; mt < 7; ++mt)
#pragma unroll
        for (int r2 = 0; r2 < 4; ++r2) {
            int t = mt * 16 + quad * 4 + r2;
            if (t < 99) cat[((size_t)t * 16 + b) * 768 + 256 + j] = acc[mt][r2];
        }
}

// ---------------- V1 GEMM: zbf[2048,768] = bf16(cat @ V1.T + b) ----------------
__global__ __launch_bounds__(256) void k_gemm_v1(const float* __restrict__ A,
                                                 const float* __restrict__ Bw,
                                                 const float* __restrict__ bias,
                                                 ushort_t* __restrict__ Cbf) {
    __shared__ __attribute__((aligned(16))) ushort_t As[64 * 32], Bs[64 * 32];
    int tid = threadIdx.x;
    int m0 = blockIdx.y * 64, n0 = blockIdx.x * 64;
    int lrow = tid >> 2, lc = (tid & 3) * 8;
    int g = tid >> 6, lane = tid & 63, lm = lane & 15, quad = lane >> 4;
    f32x4_t acc[4];
#pragma unroll
    for (int i = 0; i < 4; ++i) acc[i] = (f32x4_t){0.f, 0.f, 0.f, 0.f};
    const float* ap0 = A + (size_t)(m0 + lrow) * 768;
    const float* bp0 = Bw + (size_t)(n0 + lrow) * 768;
    for (int k0 = 0; k0 < 768; k0 += 32) {
        float av[8], bv[8];
        *(float4*)av = *(const float4*)(ap0 + k0 + lc);
        *(float4*)(av + 4) = *(const float4*)(ap0 + k0 + lc + 4);
        *(float4*)bv = *(const float4*)(bp0 + k0 + lc);
        *(float4*)(bv + 4) = *(const float4*)(bp0 + k0 + lc + 4);
        __syncthreads();
#pragma unroll
        for (int jj = 0; jj < 8; ++jj) {
            As[lrow * 32 + lc + jj] = f2bf(av[jj]);
            Bs[lrow * 32 + lc + jj] = f2bf(bv[jj]);
        }
        __syncthreads();
        bf16x8_t ah = *(const bf16x8_t*)(As + (g * 16 + lm) * 32 + quad * 8);
#pragma unroll
        for (int ns = 0; ns < 4; ++ns) {
            bf16x8_t bh = *(const bf16x8_t*)(Bs + (ns * 16 + lm) * 32 + quad * 8);
            acc[ns] = __builtin_amdgcn_mfma_f32_16x16x32_bf16(ah, bh, acc[ns], 0, 0, 0);
        }
    }
#pragma unroll
    for (int ns = 0; ns < 4; ++ns) {
        int n = n0 + ns * 16 + lm;
        float bb = bias[n];
#pragma unroll
        for (int r2 = 0; r2 < 4; ++r2) {
            int mm = m0 + g * 16 + quad * 4 + r2;
            Cbf[(size_t)mm * 768 + n] = f2bf(acc[ns][r2] + bb);
        }
    }
}

// ---------------- V2 GEMM: out[b][t][n] = softmax-input logits (bf16 MFMA) ----------------
// M-tile 512 x N-tile 64; A = zbf (bf16, L2-resident), B = V2_w fp32 staged->bf16.
__global__ __launch_bounds__(256) void k_gemm_v2(const ushort_t* __restrict__ Abf,
                                                 const float* __restrict__ V2w,
                                                 const float* __restrict__ bias,
                                                 float* __restrict__ out) {
    __shared__ __attribute__((aligned(16))) ushort_t As[512 * 32];
    __shared__ __attribute__((aligned(16))) ushort_t Bs[64 * 32];
    int tid = threadIdx.x;
    int n0 = blockIdx.x * 64;
    int m0 = blockIdx.y * 512;
    int v = tid >> 6, lane = tid & 63, lm = lane & 15, quad = lane >> 4;
    int lrow = tid >> 2, lc = (tid & 3) * 8;
    f32x4_t acc[8][4];
#pragma unroll
    for (int i = 0; i < 8; ++i)
#pragma unroll
        for (int jn = 0; jn < 4; ++jn) acc[i][jn] = (f32x4_t){0.f, 0.f, 0.f, 0.f};
    int nr = n0 + lrow;
    for (int k0 = 0; k0 < 768; k0 += 32) {
        __syncthreads();
#pragma unroll
        for (int i = 0; i < 8; ++i) {
            int row = i * 64 + lrow;
            *(uint4*)(As + row * 32 + lc) =
                *(const uint4*)(Abf + (size_t)(m0 + row) * 768 + k0 + lc);
        }
        {
            float bv8[8];
            if (nr < VV) {
                const float* bp = V2w + (size_t)nr * 768 + k0 + lc;
                *(float4*)bv8 = *(const float4*)bp;
                *(float4*)(bv8 + 4) = *(const float4*)(bp + 4);
            } else {
#pragma unroll
                for (int jj = 0; jj < 8; ++jj) bv8[jj] = 0.f;
            }
#pragma unroll
            for (int jj = 0; jj < 8; ++jj) Bs[lrow * 32 + lc + jj] = f2bf(bv8[jj]);
        }
        __syncthreads();
        bf16x8_t bn[4];
#pragma unroll
        for (int ns = 0; ns < 4; ++ns)
            bn[ns] = *(const bf16x8_t*)(Bs + (ns * 16 + lm) * 32 + quad * 8);
#pragma unroll
        for (int ms = 0; ms < 8; ++ms) {
            bf16x8_t ah = *(const bf16x8_t*)(As + (v * 128 + ms * 16 + lm) * 32 + quad * 8);
#pragma unroll
            for (int ns = 0; ns < 4; ++ns)
                acc[ms][ns] = __builtin_amdgcn_mfma_f32_16x16x32_bf16(ah, bn[ns], acc[ms][ns], 0, 0, 0);
        }
    }
#pragma unroll
    for (int ms = 0; ms < 8; ++ms)
#pragma unroll
        for (int ns = 0; ns < 4; ++ns) {
            int n = n0 + ns * 16 + lm;
            if (n >= VV) continue;
            float bb = bias[n];
#pragma unroll
            for (int r2 = 0; r2 < 4; ++r2) {
                int mrow = m0 + v * 128 + ms * 16 + quad * 4 + r2;
                if (mrow < 1584)
                    out[(size_t)(mrow & 15) * (TD * (size_t)VV) + (size_t)(mrow >> 4) * VV + n] =
                        acc[ms][ns][r2] + bb;
            }
        }
}

// ---------------- row softmax over V=50000, in place on d_out ----------------
__global__ __launch_bounds__(256) void k_softmax(float* __restrict__ out) {
    float* row = out + (size_t)blockIdx.x * VV;
    int tid = threadIdx.x;
    float m = -1e30f, s = 0.f;
    for (int i = tid; i < VV; i += 256) {
        float x = row[i];
        if (x > m) {
            s = s * expf(m - x) + 1.f;
            m = x;
        } else {
            s += expf(x - m);
        }
    }
    __shared__ float rm[256], rs[256];
    rm[tid] = m;
    rs[tid] = s;
    __syncthreads();
    for (int st = 128; st > 0; st >>= 1) {
        if (tid < st) {
            float m2 = rm[tid + st], s2 = rs[tid + st];
            float M = fmaxf(rm[tid], m2);
            rs[tid] = rs[tid] * expf(rm[tid] - M) + s2 * expf(m2 - M);
            rm[tid] = M;
        }
        __syncthreads();
    }
    float Mf = rm[0], inv = 1.f / rs[0];
    for (int i = tid; i < VV; i += 256) row[i] = expf(row[i] - Mf) * inv;
}

__global__ void k_covout(float* __restrict__ out, const float* __restrict__ cvl) {
    out[(size_t)BB * TD * VV] = cvl[0];
}

extern "C" void kernel_launch(void* const* d_in, const int* in_sizes, int n_in,
                              void* d_out, int out_size, void* d_ws, size_t ws_size,
                              hipStream_t stream) {
    const int* inputs = (const int*)d_in[0];
    const int* target = (const int*)d_in[1];
    const float* embed = (const float*)d_in[2];
    const float* Wih_f = (const float*)d_in[3];
    const float* Whh_f = (const float*)d_in[4];
    const float* b_f = (const float*)d_in[5];
    const float* Wih_b = (const float*)d_in[6];
    const float* Whh_b = (const float*)d_in[7];
    const float* b_b = (const float*)d_in[8];
    const float* Wih_d = (const float*)d_in[9];
    const float* Whh_d = (const float*)d_in[10];
    const float* b_d = (const float*)d_in[11];
    const float* Wh_w = (const float*)d_in[12];
    const float* Wh_b = (const float*)d_in[13];
    const float* Ws_w = (const float*)d_in[14];
    const float* Ws_b = (const float*)d_in[15];
    const float* Wc_w = (const float*)d_in[16];
    const float* Wc_b = (const float*)d_in[17];
    const float* v_w = (const float*)d_in[18];
    const float* v_b = (const float*)d_in[19];
    const float* V1_w = (const float*)d_in[20];
    const float* V1_b = (const float*)d_in[21];
    const float* V2_w = (const float*)d_in[22];
    const float* V2_b = (const float*)d_in[23];
    float* out = (float*)d_out;
    float* wsf = (float*)d_ws;

    float* Xf = wsf + OFF_XF;
    float* Xb = wsf + OFF_XB;
    float* Xd = wsf + OFF_XD;
    float* enc = wsf + OFF_ENC;
    float* cat = wsf + OFF_CAT;
    ushort_t* zbf = (ushort_t*)(wsf + OFF_ZBF);
    __half* attn_g = (__half*)(wsf + OFF_ATTN);
    __half* encT = (__half*)(wsf + OFF_XF);  // aliases Xf (dead after encoder)
    float* vWh = wsf + OFF_VWH;
    float* vWs = wsf + OFF_VWS;
    float* vWc = wsf + OFF_VWC;
    float* vWhw = wsf + OFF_VWHW;
    float* c0 = wsf + OFF_C0;
    ushort_t* henc = (ushort_t*)(wsf + OFF_HENC);
    ushort_t* hdec = (ushort_t*)(wsf + OFF_HDEC);
    float* p_pub = wsf + OFF_PPUB;
    float* q_pub = wsf + OFF_QPUB;
    unsigned* cnts = (unsigned*)(wsf + OFF_CNT);
    float* cvl = wsf + OFF_CVL;

    dim3 blk(256);
    k_init<<<32, 256, 0, stream>>>(wsf + OFF_HENC, (int)ZERO_N);
    k_precomp<<<1, 256, 0, stream>>>(v_w, Ws_w, Wc_w, Wh_w, Wh_b, Ws_b, Wc_b, v_b, vWs, vWc,
                                     vWhw, c0);
    k_xproj<<<dim3(16, 100), blk, 0, stream>>>(embed, inputs, LL, Wih_f, b_f, Xf, 6400);
    k_xproj<<<dim3(16, 100), blk, 0, stream>>>(embed, inputs, LL, Wih_b, b_b, Xb, 6400);
    k_xproj<<<dim3(16, 25), blk, 0, stream>>>(embed, target, 100, Wih_d, b_d, Xd, 1584);
    k_enc_pers<<<32, blk, 0, stream>>>(Xf, Xb, Whh_f, Whh_b, henc, cnts, enc);
    k_vwh<<<25, 256, 0, stream>>>(enc, vWhw, vWh);
    k_transpose<<<dim3(7, 8, 16), blk, 0, stream>>>(enc, encT);
    k_dec_pers<<<16, blk, 0, stream>>>(Xd, Whh_d, hdec, cnts + 32, vWh, vWs, vWc, c0, p_pub,
                                       q_pub, cat, attn_g, cvl);
    k_ctx_gemm<<<dim3(8, 16), blk, 0, stream>>>(attn_g, encT, cat);
    k_gemm_v1<<<dim3(12, 25), blk, 0, stream>>>(cat, V1_w, V1_b, zbf);
    k_gemm_v2<<<dim3(782, 4), blk, 0, stream>>>(zbf, V2_w, V2_b, out);
    k_softmax<<<1584, 256, 0, stream>>>(out);
    k_covout<<<1, 1, 0, stream>>>(out, cvl);
}

// Round 2
// 3058.433 us; speedup vs baseline: 1.3244x; 1.1995x over previous
//
#include <hip/hip_runtime.h>
#include <hip/hip_bf16.h>
#include <hip/hip_fp16.h>

// BiLSTM encoder (L=400) + coverage-attention LSTM decoder (T-1=99) + V=50000 softmax.
// B=16, E=128, H=256, 4H=1024, 2H=512, 3H=768.
//
// Round-4 changes (persistent kernels only):
//  - LDS-staged h exchange: each WG pulls the 16KB h hi/lo plane pair ONCE
//    (4 coherent dwordx4/thread) into LDS (row stride 528B = bank-optimal),
//    MFMA fragments read from LDS. Replaces 4x-redundant 64KB/WG coherent
//    register loads (2MB/step of IC traffic -> 512KB/step).
//  - x-prefetch issued right after cc-wait (pinned via sched_barrier), consumed
//    after the pre-barrier drain -> drain waits ONLY the 2 coherent h stores.
//  - MFMA split into 3 independent accumulator chains (shorter dep chain).
//  - decoder: next-step cc loads issued immediately post-barrier; their L3
//    latency hides under the attention phase.

#define BB 16
#define LL 400
#define TD 99
#define G4 1024
#define H2 512
#define H3 768
#define VV 50000

typedef __attribute__((ext_vector_type(8))) short bf16x8_t;
typedef __attribute__((ext_vector_type(8))) _Float16 f16x8_t;
typedef __attribute__((ext_vector_type(4))) float f32x4_t;
typedef __attribute__((ext_vector_type(4))) unsigned int u32x4_t;
typedef unsigned short ushort_t;

static constexpr size_t OFF_XF   = 0;            // 6,553,600  (aliased by encT f16 after encoder)
static constexpr size_t OFF_XB   = 6553600;      // 6,553,600
static constexpr size_t OFF_XD   = 13107200;     // 1,622,016
static constexpr size_t OFF_ENC  = 14729216;     // 3,276,800
static constexpr size_t OFF_CAT  = 18006016;     // 1,216,512
static constexpr size_t OFF_ZBF  = 19222528;     // 786,432 floats = ushort[2048*768]
static constexpr size_t OFF_ATTN = 20008960;     // 372,736 floats = half[16*112*416]
static constexpr size_t OFF_VWH  = 20381696;     // 6400
static constexpr size_t OFF_VWS  = 20388096;     // 256
static constexpr size_t OFF_VWC  = 20388352;     // 512
static constexpr size_t OFF_VWHW = 20388864;     // 512
static constexpr size_t OFF_C0   = 20389376;     // 16
static constexpr size_t OFF_HENC = 20389392;     // 16,384 floats = ushort[2][2][2][4096]
static constexpr size_t OFF_HDEC = 20405776;     // 8,192 floats = ushort[2][2][4096]
static constexpr size_t OFF_PPUB = 20413968;     // 512
static constexpr size_t OFF_QPUB = 20414480;     // 32
static constexpr size_t OFF_CNT  = 20414512;     // 64 (u32 counters: +0 enc dir0, +16 enc dir1, +32 dec)
static constexpr size_t OFF_CVL  = 20414576;     // 16
static constexpr size_t OFF_END  = 20414592;     // ~81.7 MB
static constexpr size_t ZERO_N   = OFF_END - OFF_HENC;  // 25,200

__device__ __forceinline__ ushort_t f2bf(float x) {
    unsigned u = __float_as_uint(x);
    unsigned r = u + 0x7FFFu + ((u >> 16) & 1u);
    return (ushort_t)(r >> 16);
}
__device__ __forceinline__ float bf2f(ushort_t h) {
    return __uint_as_float(((unsigned)h) << 16);
}
__device__ __forceinline__ float wred_sum(float v) {
#pragma unroll
    for (int o = 32; o; o >>= 1) v += __shfl_xor(v, o);
    return v;
}
__device__ __forceinline__ float wred_max(float v) {
#pragma unroll
    for (int o = 32; o; o >>= 1) v = fmaxf(v, __shfl_xor(v, o));
    return v;
}
__device__ __forceinline__ float sigf(float x) { return 1.f / (1.f + expf(-x)); }

// Issue 4 coherent 16B loads covering this thread's 64B share of the 16KB
// h plane pair (hi 8KB | lo 8KB). Results invalid until CC_WAIT.
#define CC_ISSUE(pl)                                                               \
    asm volatile("global_load_dwordx4 %0, %4, off sc0 sc1\n\t"                     \
                 "global_load_dwordx4 %1, %5, off sc0 sc1\n\t"                     \
                 "global_load_dwordx4 %2, %6, off sc0 sc1\n\t"                     \
                 "global_load_dwordx4 %3, %7, off sc0 sc1"                         \
                 : "=&v"(r0), "=&v"(r1), "=&v"(r2), "=&v"(r3)                      \
                 : "v"(pl), "v"((pl) + 4096), "v"((pl) + 8192), "v"((pl) + 12288)  \
                 : "memory")

#define CC_WAIT()                                                                  \
    do {                                                                           \
        asm volatile("s_waitcnt vmcnt(0)" ::: "memory");                           \
        __builtin_amdgcn_sched_barrier(0);                                         \
    } while (0)

// LDS staging layout: 2 planes (hi, lo), each 16 rows x 512B, row stride 528B
// (528B = 132 dwords -> row r starts at bank (4r)%32 -> optimal 8-slot spread
// for both the b128 staging writes and the b128 fragment reads).
#define HX_BYTES (2 * 8448)

// ---------------- init: zero state region ----------------
__global__ void k_init(float* __restrict__ p, int n) {
    for (int i = blockIdx.x * blockDim.x + threadIdx.x; i < n; i += gridDim.x * blockDim.x)
        p[i] = 0.0f;
}

// ---------------- precompute v-folded attention vectors ----------------
__global__ void k_precomp(const float* __restrict__ v, const float* __restrict__ Ws_w,
                          const float* __restrict__ Wc_w, const float* __restrict__ Wh_w,
                          const float* __restrict__ Wh_b, const float* __restrict__ Ws_b,
                          const float* __restrict__ Wc_b, const float* __restrict__ v_b,
                          float* __restrict__ vWs, float* __restrict__ vWc,
                          float* __restrict__ vWhw, float* __restrict__ c0) {
    int tid = threadIdx.x;
    {
        float a = 0.f;
        for (int j = 0; j < 256; ++j) a += v[j] * Ws_w[j * 256 + tid];
        vWs[tid] = a;
    }
    for (int k = tid; k < 400; k += 256) {
        float a = 0.f;
        for (int j = 0; j < 256; ++j) a += v[j] * Wc_w[j * 400 + k];
        vWc[k] = a;
    }
    for (int k = tid; k < 512; k += 256) {
        float a = 0.f;
        for (int j = 0; j < 256; ++j) a += v[j] * Wh_w[j * 512 + k];
        vWhw[k] = a;
    }
    if (tid == 0) {
        float a = 0.f;
        for (int j = 0; j < 256; ++j) a += v[j] * (Wh_b[j] + Ws_b[j] + Wc_b[j]);
        c0[0] = a + v_b[0];
    }
}

// ---------------- gather x-projection GEMM (split-bf16, 3 MFMA) ----------------
// C[M,1024] = embed[tok(m)] @ Wih.T + bias ; tok(m) = toks[(m&15)*S + (m>>4)]
__global__ __launch_bounds__(256) void k_xproj(
    const float* __restrict__ emb, const int* __restrict__ toks, int tokStride,
    const float* __restrict__ Wih, const float* __restrict__ bias,
    float* __restrict__ C, int M) {
    __shared__ __attribute__((aligned(16))) ushort_t Ah[64 * 32], Al[64 * 32];
    __shared__ __attribute__((aligned(16))) ushort_t Bh[64 * 32], Bl[64 * 32];
    int tid = threadIdx.x;
    int m0 = blockIdx.y * 64, n0 = blockIdx.x * 64;
    int lrow = tid >> 2, lc = (tid & 3) * 8;
    int g = tid >> 6, lane = tid & 63, lm = lane & 15, quad = lane >> 4;
    f32x4_t acc[4];
#pragma unroll
    for (int i = 0; i < 4; ++i) acc[i] = (f32x4_t){0.f, 0.f, 0.f, 0.f};
    int mr = m0 + lrow;
    int l = mr >> 4, bb2 = mr & 15;
    int tok = (mr < M) ? toks[bb2 * tokStride + l] : 0;
    const float* arow = emb + (size_t)tok * 128;
    const float* brow = Wih + (size_t)(n0 + lrow) * 128;
    for (int k0 = 0; k0 < 128; k0 += 32) {
        float av[8], bv[8];
        *(float4*)(av) = *(const float4*)(arow + k0 + lc);
        *(float4*)(av + 4) = *(const float4*)(arow + k0 + lc + 4);
        *(float4*)(bv) = *(const float4*)(brow + k0 + lc);
        *(float4*)(bv + 4) = *(const float4*)(brow + k0 + lc + 4);
        __syncthreads();
#pragma unroll
        for (int j = 0; j < 8; ++j) {
            ushort_t h = f2bf(av[j]);
            Ah[lrow * 32 + lc + j] = h;
            Al[lrow * 32 + lc + j] = f2bf(av[j] - bf2f(h));
            ushort_t h2 = f2bf(bv[j]);
            Bh[lrow * 32 + lc + j] = h2;
            Bl[lrow * 32 + lc + j] = f2bf(bv[j] - bf2f(h2));
        }
        __syncthreads();
        bf16x8_t ah = *(const bf16x8_t*)(Ah + (g * 16 + lm) * 32 + quad * 8);
        bf16x8_t al = *(const bf16x8_t*)(Al + (g * 16 + lm) * 32 + quad * 8);
#pragma unroll
        for (int ns = 0; ns < 4; ++ns) {
            bf16x8_t bh = *(const bf16x8_t*)(Bh + (ns * 16 + lm) * 32 + quad * 8);
            bf16x8_t bl = *(const bf16x8_t*)(Bl + (ns * 16 + lm) * 32 + quad * 8);
            acc[ns] = __builtin_amdgcn_mfma_f32_16x16x32_bf16(ah, bh, acc[ns], 0, 0, 0);
            acc[ns] = __builtin_amdgcn_mfma_f32_16x16x32_bf16(ah, bl, acc[ns], 0, 0, 0);
            acc[ns] = __builtin_amdgcn_mfma_f32_16x16x32_bf16(al, bh, acc[ns], 0, 0, 0);
        }
    }
#pragma unroll
    for (int ns = 0; ns < 4; ++ns) {
        int n = n0 + ns * 16 + lm;
        float bb = bias[n];
#pragma unroll
        for (int r2 = 0; r2 < 4; ++r2) {
            int mm = m0 + g * 16 + quad * 4 + r2;
            if (mm < M) C[(size_t)mm * 1024 + n] = acc[ns][r2] + bb;
        }
    }
}

// ---------------- persistent encoder: 32 WGs = 2 dirs x 16 k-slices ----------------
__global__ __launch_bounds__(256) void k_enc_pers(
    const float* __restrict__ Xf, const float* __restrict__ Xb,
    const float* __restrict__ Whh_f, const float* __restrict__ Whh_b,
    ushort_t* __restrict__ hbuf, unsigned* __restrict__ cnts, float* __restrict__ enc) {
    __shared__ float pre[1024];
    __shared__ __attribute__((aligned(16))) char hx[HX_BYTES];
    int bx = blockIdx.x;
    int q = bx >> 3, r = bx & 7;
    int dir = r >> 2;
    int w = q * 4 + (r & 3);            // XCD-split: each dir lives on 4 XCDs
    const float* Whh = dir ? Whh_b : Whh_f;
    const float* X = dir ? Xb : Xf;
    unsigned* cnt = cnts + dir * 16;
    ushort_t* hb = hbuf + dir * 16384;  // [par][plane][4096]
    int tid = threadIdx.x;
    int g = tid >> 6, lane = tid & 63, lm = lane & 15, quad = lane >> 4;
    int gbase = 256 * g + 16 * w;
    bf16x8_t Bh[8], Bl[8];
    {
        const float* wr = Whh + (size_t)(gbase + lm) * 256;
#pragma unroll
        for (int kk = 0; kk < 8; ++kk) {
            union { bf16x8_t v; ushort_t u[8]; } hh, ll;
#pragma unroll
            for (int j = 0; j < 8; ++j) {
                float x = wr[kk * 32 + quad * 8 + j];
                ushort_t hi = f2bf(x);
                hh.u[j] = hi;
                ll.u[j] = f2bf(x - bf2f(hi));
            }
            Bh[kk] = hh.v;
            Bl[kk] = ll.v;
        }
    }
    int m = tid >> 4, kk16 = tid & 15;
    int k = w * 16 + kk16;
    // staging addresses (loop-invariant): global byte gb of the 16KB pair ->
    // LDS plane*8448 + row*528 + col
    int wa[4];
#pragma unroll
    for (int j = 0; j < 4; ++j) {
        int gb = tid * 16 + j * 4096;
        wa[j] = (gb >> 13) * 8448 + ((gb >> 9) & 15) * 528 + (gb & 511);
    }
    const char* fha = hx + lm * 528 + quad * 16;  // hi-plane fragment base
    const char* fla = fha + 8448;                 // lo-plane fragment base
    const char* pp0 = (const char*)hb + tid * 16;
    const char* pp1 = pp0 + 16384;
    ushort_t* soA = hb + 8192 + m * 256 + k;      // out when par=0 -> buf1
    ushort_t* soB = hb + m * 256 + k;             // out when par=1 -> buf0
    float c = 0.f;
    int l0 = dir ? 399 : 0;
    const float* Xr0 = X + (size_t)(l0 * 16 + m) * 1024;
    float x0 = Xr0[k], x1 = Xr0[256 + k], x2 = Xr0[512 + k], x3 = Xr0[768 + k];
    float xn0 = 0.f, xn1 = 0.f, xn2 = 0.f, xn3 = 0.f;
    u32x4_t r0, r1, r2, r3;
    for (int t = 0; t < 400; ++t) {
        int par = t & 1;
        const char* pl = par ? pp1 : pp0;
        CC_ISSUE(pl);
        CC_WAIT();
        // x prefetch for t+1, issued here so its HBM latency hides under
        // the MFMA/act phase (consumed after the pre-barrier drain)
        if (t < 399) {
            int ln = dir ? (398 - t) : (t + 1);
            const float* Xr = X + (size_t)(ln * 16 + m) * 1024;
            xn0 = Xr[k]; xn1 = Xr[256 + k]; xn2 = Xr[512 + k]; xn3 = Xr[768 + k];
        }
        __builtin_amdgcn_sched_barrier(0);  // pin x issue above the compute
        *(u32x4_t*)(hx + wa[0]) = r0;
        *(u32x4_t*)(hx + wa[1]) = r1;
        *(u32x4_t*)(hx + wa[2]) = r2;
        *(u32x4_t*)(hx + wa[3]) = r3;
        __syncthreads();
        f32x4_t a0 = (f32x4_t){0.f, 0.f, 0.f, 0.f};
        f32x4_t a1 = a0, a2 = a0;
#pragma unroll
        for (int kk = 0; kk < 8; ++kk) {
            bf16x8_t ah = *(const bf16x8_t*)(fha + kk * 64);
            bf16x8_t al = *(const bf16x8_t*)(fla + kk * 64);
            a0 = __builtin_amdgcn_mfma_f32_16x16x32_bf16(ah, Bh[kk], a0, 0, 0, 0);
            a1 = __builtin_amdgcn_mfma_f32_16x16x32_bf16(ah, Bl[kk], a1, 0, 0, 0);
            a2 = __builtin_amdgcn_mfma_f32_16x16x32_bf16(al, Bh[kk], a2, 0, 0, 0);
        }
        f32x4_t acc = a0 + a1 + a2;
#pragma unroll
        for (int r2i = 0; r2i < 4; ++r2i) pre[g * 256 + (quad * 4 + r2i) * 16 + lm] = acc[r2i];
        __syncthreads();
        float gi = pre[tid] + x0;
        float gf = pre[256 + tid] + x1;
        float gg = pre[512 + tid] + x2;
        float go = pre[768 + tid] + x3;
        int l = dir ? (399 - t) : t;
        c = sigf(gf) * c + sigf(gi) * tanhf(gg);
        float h = sigf(go) * tanhf(c);
        enc[((size_t)m * 400 + l) * 512 + dir * 256 + k] = h;
        ushort_t hh = f2bf(h);
        unsigned hhi32 = hh;
        unsigned hlo32 = f2bf(h - bf2f(hh));
        ushort_t* so = par ? soB : soA;
        asm volatile("global_store_short %0, %2, off sc0 sc1\n\t"
                     "global_store_short %1, %3, off sc0 sc1"
                     :: "v"(so), "v"(so + 4096), "v"(hhi32), "v"(hlo32) : "memory");
        // drain: x loads long retired (issued at top); enc store hits L2 fast;
        // only the two coherent h stores are actually waited on here.
        asm volatile("s_waitcnt vmcnt(0)" ::: "memory");
        __builtin_amdgcn_sched_barrier(0);
        x0 = xn0; x1 = xn1; x2 = xn2; x3 = xn3;  // safe: vmcnt(0) retired them
        __syncthreads();
        if (tid == 0) {
            __hip_atomic_fetch_add(cnt, 1u, __ATOMIC_RELAXED, __HIP_MEMORY_SCOPE_AGENT);
            unsigned tgt = (unsigned)(t + 1) * 16u;
            while (__hip_atomic_load(cnt, __ATOMIC_RELAXED, __HIP_MEMORY_SCOPE_AGENT) < tgt)
                __builtin_amdgcn_s_sleep(1);
        }
        __syncthreads();
    }
}

// ---------------- vWh[b*L+l] = vWhw . enc[b,l,:] ----------------
__global__ void k_vwh(const float* __restrict__ enc, const float* __restrict__ vWhw,
                      float* __restrict__ vWh) {
    int rr = blockIdx.x * 256 + threadIdx.x;
    const float* row = enc + (size_t)rr * H2;
    float acc = 0.f;
#pragma unroll 4
    for (int k = 0; k < H2; k += 4) {
        float4 e = *(const float4*)(row + k);
        float4 wv = *(const float4*)(vWhw + k);
        acc += e.x * wv.x + e.y * wv.y + e.z * wv.z + e.w * wv.w;
    }
    vWh[rr] = acc;
}

// ---------------- transpose enc -> encT f16 [b][j][l(416, zero-padded)] ----------------
__global__ __launch_bounds__(256) void k_transpose(const float* __restrict__ enc,
                                                   __half* __restrict__ encT) {
    __shared__ float tb[64][65];
    int lt = blockIdx.x, jt = blockIdx.y, b = blockIdx.z;
    int l0 = lt * 64, j0 = jt * 64;
    int tid = threadIdx.x;
    for (int i = tid; i < 4096; i += 256) {
        int li = i >> 6, jj = i & 63;
        int l = l0 + li;
        tb[jj][li] = (l < 400) ? enc[((size_t)b * 400 + l) * 512 + j0 + jj] : 0.f;
    }
    __syncthreads();
    for (int i = tid; i < 4096; i += 256) {
        int jj = i >> 6, li = i & 63;
        int l = l0 + li;
        if (l < 416) encT[((size_t)b * 512 + j0 + jj) * 416 + l] = __float2half(tb[jj][li]);
    }
}

// ---------------- persistent decoder: 16 WGs (k-slice for LSTM, batch for attention) ----
__global__ __launch_bounds__(256) void k_dec_pers(
    const float* __restrict__ Xd, const float* __restrict__ Whh_d,
    ushort_t* __restrict__ hbuf, unsigned* __restrict__ cnt,
    const float* __restrict__ vWh, const float* __restrict__ vWs,
    const float* __restrict__ vWc, const float* __restrict__ c0g,
    float* __restrict__ p_pub, float* __restrict__ q_pub, float* __restrict__ cat,
    __half* __restrict__ attn_g, float* __restrict__ cvl) {
    __shared__ float pre[1024];
    __shared__ float covL[400];
    __shared__ float vred[256];
    __shared__ float psh[256];
    __shared__ float vswcS[16];
    __shared__ float rr[8];
    __shared__ __attribute__((aligned(16))) char hx[HX_BYTES];
    int w = blockIdx.x;
    int b = w;
    int tid = threadIdx.x;
    int g = tid >> 6, lane = tid & 63, lm = lane & 15, quad = lane >> 4;
    int gbase = 256 * g + 16 * w;
    bf16x8_t Bh[8], Bl[8];
    {
        const float* wr = Whh_d + (size_t)(gbase + lm) * 256;
#pragma unroll
        for (int kk = 0; kk < 8; ++kk) {
            union { bf16x8_t v; ushort_t u[8]; } hh, ll;
#pragma unroll
            for (int j = 0; j < 8; ++j) {
                float x = wr[kk * 32 + quad * 8 + j];
                ushort_t hi = f2bf(x);
                hh.u[j] = hi;
                ll.u[j] = f2bf(x - bf2f(hi));
            }
            Bh[kk] = hh.v;
            Bl[kk] = ll.v;
        }
    }
    int m = tid >> 4, kk16 = tid & 15;
    int k = w * 16 + kk16;
    int wa[4];
#pragma unroll
    for (int j = 0; j < 4; ++j) {
        int gb = tid * 16 + j * 4096;
        wa[j] = (gb >> 13) * 8448 + ((gb >> 9) & 15) * 528 + (gb & 511);
    }
    const char* fha = hx + lm * 528 + quad * 16;
    const char* fla = fha + 8448;
    const char* pp0 = (const char*)hbuf + tid * 16;
    const char* pp1 = pp0 + 16384;
    ushort_t* soA = hbuf + 8192 + m * 256 + k;
    ushort_t* soB = hbuf + m * 256 + k;
    float c = 0.f, cl_acc = 0.f;
    for (int i = tid; i < 400; i += 256) covL[i] = 0.f;
    float c0v = c0g[0];
    float vwsk = vWs[k];
    const float* Xr0 = Xd + (size_t)m * 1024;
    float x0 = Xr0[k], x1 = Xr0[256 + k], x2 = Xr0[512 + k], x3 = Xr0[768 + k];
    float xn0 = 0.f, xn1 = 0.f, xn2 = 0.f, xn3 = 0.f;
    u32x4_t r0, r1, r2, r3;
    CC_ISSUE(pp0);  // prologue: h(-1)=0 plane pair (par0)
    __syncthreads();
    for (int t = 0; t < TD; ++t) {
        int par = t & 1;
        CC_WAIT();  // cc loads were issued last iteration (hidden under attention)
        if (t < TD - 1) {
            const float* Xr = Xd + (size_t)((t + 1) * 16 + m) * 1024;
            xn0 = Xr[k]; xn1 = Xr[256 + k]; xn2 = Xr[512 + k]; xn3 = Xr[768 + k];
        }
        __builtin_amdgcn_sched_barrier(0);
        *(u32x4_t*)(hx + wa[0]) = r0;
        *(u32x4_t*)(hx + wa[1]) = r1;
        *(u32x4_t*)(hx + wa[2]) = r2;
        *(u32x4_t*)(hx + wa[3]) = r3;
        // q = vWc . cov (cov from previous step) overlaps the staging
        float qv = 0.f;
        for (int i = tid; i < 400; i += 256) qv += vWc[i] * covL[i];
        qv = wred_sum(qv);
        __syncthreads();
        // ---- LSTM MFMA (3 independent chains) ----
        f32x4_t a0 = (f32x4_t){0.f, 0.f, 0.f, 0.f};
        f32x4_t a1 = a0, a2 = a0;
#pragma unroll
        for (int kk = 0; kk < 8; ++kk) {
            bf16x8_t ah = *(const bf16x8_t*)(fha + kk * 64);
            bf16x8_t al = *(const bf16x8_t*)(fla + kk * 64);
            a0 = __builtin_amdgcn_mfma_f32_16x16x32_bf16(ah, Bh[kk], a0, 0, 0, 0);
            a1 = __builtin_amdgcn_mfma_f32_16x16x32_bf16(ah, Bl[kk], a1, 0, 0, 0);
            a2 = __builtin_amdgcn_mfma_f32_16x16x32_bf16(al, Bh[kk], a2, 0, 0, 0);
        }
        f32x4_t acc = a0 + a1 + a2;
#pragma unroll
        for (int r2i = 0; r2i < 4; ++r2i) pre[g * 256 + (quad * 4 + r2i) * 16 + lm] = acc[r2i];
        if (lane == 0) rr[g] = qv;
        __syncthreads();
        // ---- activations ----
        float gi = pre[tid] + x0;
        float gf = pre[256 + tid] + x1;
        float gg = pre[512 + tid] + x2;
        float go = pre[768 + tid] + x3;
        c = sigf(gf) * c + sigf(gi) * tanhf(gg);
        float h = sigf(go) * tanhf(c);
        cat[((size_t)t * 16 + m) * 768 + k] = h;
        ushort_t hh = f2bf(h);
        unsigned hhi32 = hh;
        unsigned hlo32 = f2bf(h - bf2f(hh));
        ushort_t* so = par ? soB : soA;
        asm volatile("global_store_short %0, %2, off sc0 sc1\n\t"
                     "global_store_short %1, %3, off sc0 sc1"
                     :: "v"(so), "v"(so + 4096), "v"(hhi32), "v"(hlo32) : "memory");
        psh[tid] = vwsk * h;
        if (tid == 0)
            __hip_atomic_store(&q_pub[par * 16 + b], rr[0] + rr[1] + rr[2] + rr[3],
                               __ATOMIC_RELAXED, __HIP_MEMORY_SCOPE_AGENT);
        __syncthreads();
        if (tid < 16) {
            float s = 0.f;
#pragma unroll
            for (int j = 0; j < 16; ++j) s += psh[tid * 16 + j];
            __hip_atomic_store(&p_pub[par * 256 + w * 16 + tid], s,
                               __ATOMIC_RELAXED, __HIP_MEMORY_SCOPE_AGENT);
        }
        // drain coherent stores (asm h stores + builtin atomics) before signaling
        asm volatile("s_waitcnt vmcnt(0)" ::: "memory");
        __builtin_amdgcn_sched_barrier(0);
        x0 = xn0; x1 = xn1; x2 = xn2; x3 = xn3;
        __syncthreads();
        // ---- grid barrier (fence-free) ----
        if (tid == 0) {
            __hip_atomic_fetch_add(cnt, 1u, __ATOMIC_RELAXED, __HIP_MEMORY_SCOPE_AGENT);
            unsigned tgt = (unsigned)(t + 1) * 16u;
            while (__hip_atomic_load(cnt, __ATOMIC_RELAXED, __HIP_MEMORY_SCOPE_AGENT) < tgt)
                __builtin_amdgcn_s_sleep(1);
        }
        __syncthreads();
        // issue next step's cc loads NOW; latency hides under attention
        if (t < TD - 1) {
            const char* pln = par ? pp0 : pp1;
            CC_ISSUE(pln);
        }
        // ---- attention (WG = batch b) ----
        vred[tid] = __hip_atomic_load(&p_pub[par * 256 + tid], __ATOMIC_RELAXED,
                                      __HIP_MEMORY_SCOPE_AGENT);
        __syncthreads();
        if (tid < 128) vred[tid] += vred[tid + 128];
        __syncthreads();
        if (tid < 64) vred[tid] += vred[tid + 64];
        __syncthreads();
        if (tid < 32) vred[tid] += vred[tid + 32];
        __syncthreads();
        if (tid < 16)
            vswcS[tid] = vred[tid] + vred[tid + 16] +
                         __hip_atomic_load(&q_pub[par * 16 + tid], __ATOMIC_RELAXED,
                                           __HIP_MEMORY_SCOPE_AGENT);
        __syncthreads();
        bool has2 = tid < 144;
        float vs = vswcS[tid & 15] + c0v;  // (b*400+l)%16 == l%16 == tid%16 for both l=tid, tid+256
        float lg1 = vWh[b * 400 + tid] + vs;
        float lg2 = has2 ? (vWh[b * 400 + 256 + tid] + vs) : -1e30f;
        float mx = wred_max(fmaxf(lg1, lg2));
        if (lane == 0) rr[g] = mx;
        __syncthreads();
        float M = fmaxf(fmaxf(rr[0], rr[1]), fmaxf(rr[2], rr[3]));
        float e1 = expf(lg1 - M);
        float e2 = has2 ? expf(lg2 - M) : 0.f;
        float sv = wred_sum(e1 + e2);
        if (lane == 0) rr[4 + g] = sv;
        __syncthreads();
        float inv = 1.f / (rr[4] + rr[5] + rr[6] + rr[7]);
        float a1v = e1 * inv, a2v = e2 * inv;
        float cv1 = covL[tid];
        float cl = fminf(a1v, cv1);
        covL[tid] = cv1 + a1v;
        __half* arow = attn_g + ((size_t)b * 112 + t) * 416;
        arow[tid] = __float2half(a1v);
        if (has2) {
            float cv2 = covL[tid + 256];
            cl += fminf(a2v, cv2);
            covL[tid + 256] = cv2 + a2v;
            arow[256 + tid] = __float2half(a2v);
        }
        cl = wred_sum(cl);
        __syncthreads();
        if (lane == 0) rr[g] = cl;
        __syncthreads();
        if (tid == 0) cl_acc += rr[0] + rr[1] + rr[2] + rr[3];
        __syncthreads();   // covL updates visible before next step's q
    }
    if (tid == 0) atomicAdd(cvl, cl_acc);
}

// ---------------- batched context GEMM: cat[t*16+b][256:768] = attn @ enc ----------------
__global__ __launch_bounds__(256) void k_ctx_gemm(const __half* __restrict__ attn_g,
                                                  const __half* __restrict__ encT,
                                                  float* __restrict__ cat) {
    int jt = blockIdx.x, b = blockIdx.y;
    int tid = threadIdx.x, v = tid >> 6, lane = tid & 63, lm = lane & 15, quad = lane >> 4;
    f32x4_t acc[7];
#pragma unroll
    for (int i = 0; i < 7; ++i) acc[i] = (f32x4_t){0.f, 0.f, 0.f, 0.f};
    int j = jt * 64 + v * 16 + lm;
    const _Float16* brow = (const _Float16*)(encT + ((size_t)b * 512 + j) * 416);
    const _Float16* abase = (const _Float16*)(attn_g + (size_t)b * 112 * 416);
    for (int k0 = 0; k0 < 416; k0 += 32) {
        f16x8_t bf = *(const f16x8_t*)(brow + k0 + quad * 8);
#pragma unroll
        for (int mt = 0; mt < 7; ++mt) {
            f16x8_t af = *(const f16x8_t*)(abase + (size_t)(mt * 16 + lm) * 416 + k0 + quad * 8);
            acc[mt] = __builtin_amdgcn_mfma_f32_16x16x32_f16(af, bf, acc[mt], 0, 0, 0);
        }
    }
#pragma unroll
    for (int mt = 0; mt < 7; ++mt)
#pragma unroll
        for (int r2 = 0; r2 < 4; ++r2) {
            int t = mt * 16 + quad * 4 + r2;
            if (t < 99) cat[((size_t)t * 16 + b) * 768 + 256 + j] = acc[mt][r2];
        }
}

// ---------------- V1 GEMM: zbf[2048,768] = bf16(cat @ V1.T + b) ----------------
__global__ __launch_bounds__(256) void k_gemm_v1(const float* __restrict__ A,
                                                 const float* __restrict__ Bw,
                                                 const float* __restrict__ bias,
                                                 ushort_t* __restrict__ Cbf) {
    __shared__ __attribute__((aligned(16))) ushort_t As[64 * 32], Bs[64 * 32];
    int tid = threadIdx.x;
    int m0 = blockIdx.y * 64, n0 = blockIdx.x * 64;
    int lrow = tid >> 2, lc = (tid & 3) * 8;
    int g = tid >> 6, lane = tid & 63, lm = lane & 15, quad = lane >> 4;
    f32x4_t acc[4];
#pragma unroll
    for (int i = 0; i < 4; ++i) acc[i] = (f32x4_t){0.f, 0.f, 0.f, 0.f};
    const float* ap0 = A + (size_t)(m0 + lrow) * 768;
    const float* bp0 = Bw + (size_t)(n0 + lrow) * 768;
    for (int k0 = 0; k0 < 768; k0 += 32) {
        float av[8], bv[8];
        *(float4*)av = *(const float4*)(ap0 + k0 + lc);
        *(float4*)(av + 4) = *(const float4*)(ap0 + k0 + lc + 4);
        *(float4*)bv = *(const float4*)(bp0 + k0 + lc);
        *(float4*)(bv + 4) = *(const float4*)(bp0 + k0 + lc + 4);
        __syncthreads();
#pragma unroll
        for (int jj = 0; jj < 8; ++jj) {
            As[lrow * 32 + lc + jj] = f2bf(av[jj]);
            Bs[lrow * 32 + lc + jj] = f2bf(bv[jj]);
        }
        __syncthreads();
        bf16x8_t ah = *(const bf16x8_t*)(As + (g * 16 + lm) * 32 + quad * 8);
#pragma unroll
        for (int ns = 0; ns < 4; ++ns) {
            bf16x8_t bh = *(const bf16x8_t*)(Bs + (ns * 16 + lm) * 32 + quad * 8);
            acc[ns] = __builtin_amdgcn_mfma_f32_16x16x32_bf16(ah, bh, acc[ns], 0, 0, 0);
        }
    }
#pragma unroll
    for (int ns = 0; ns < 4; ++ns) {
        int n = n0 + ns * 16 + lm;
        float bb = bias[n];
#pragma unroll
        for (int r2 = 0; r2 < 4; ++r2) {
            int mm = m0 + g * 16 + quad * 4 + r2;
            Cbf[(size_t)mm * 768 + n] = f2bf(acc[ns][r2] + bb);
        }
    }
}

// ---------------- V2 GEMM: out[b][t][n] = softmax-input logits (bf16 MFMA) ----------------
// M-tile 512 x N-tile 64; A = zbf (bf16, L2-resident), B = V2_w fp32 staged->bf16.
__global__ __launch_bounds__(256) void k_gemm_v2(const ushort_t* __restrict__ Abf,
                                                 const float* __restrict__ V2w,
                                                 const float* __restrict__ bias,
                                                 float* __restrict__ out) {
    __shared__ __attribute__((aligned(16))) ushort_t As[512 * 32];
    __shared__ __attribute__((aligned(16))) ushort_t Bs[64 * 32];
    int tid = threadIdx.x;
    int n0 = blockIdx.x * 64;
    int m0 = blockIdx.y * 512;
    int v = tid >> 6, lane = tid & 63, lm = lane & 15, quad = lane >> 4;
    int lrow = tid >> 2, lc = (tid & 3) * 8;
    f32x4_t acc[8][4];
#pragma unroll
    for (int i = 0; i < 8; ++i)
#pragma unroll
        for (int jn = 0; jn < 4; ++jn) acc[i][jn] = (f32x4_t){0.f, 0.f, 0.f, 0.f};
    int nr = n0 + lrow;
    for (int k0 = 0; k0 < 768; k0 += 32) {
        __syncthreads();
#pragma unroll
        for (int i = 0; i < 8; ++i) {
            int row = i * 64 + lrow;
            *(uint4*)(As + row * 32 + lc) =
                *(const uint4*)(Abf + (size_t)(m0 + row) * 768 + k0 + lc);
        }
        {
            float bv8[8];
            if (nr < VV) {
                const float* bp = V2w + (size_t)nr * 768 + k0 + lc;
                *(float4*)bv8 = *(const float4*)bp;
                *(float4*)(bv8 + 4) = *(const float4*)(bp + 4);
            } else {
#pragma unroll
                for (int jj = 0; jj < 8; ++jj) bv8[jj] = 0.f;
            }
#pragma unroll
            for (int jj = 0; jj < 8; ++jj) Bs[lrow * 32 + lc + jj] = f2bf(bv8[jj]);
        }
        __syncthreads();
        bf16x8_t bn[4];
#pragma unroll
        for (int ns = 0; ns < 4; ++ns)
            bn[ns] = *(const bf16x8_t*)(Bs + (ns * 16 + lm) * 32 + quad * 8);
#pragma unroll
        for (int ms = 0; ms < 8; ++ms) {
            bf16x8_t ah = *(const bf16x8_t*)(As + (v * 128 + ms * 16 + lm) * 32 + quad * 8);
#pragma unroll
            for (int ns = 0; ns < 4; ++ns)
                acc[ms][ns] = __builtin_amdgcn_mfma_f32_16x16x32_bf16(ah, bn[ns], acc[ms][ns], 0, 0, 0);
        }
    }
#pragma unroll
    for (int ms = 0; ms < 8; ++ms)
#pragma unroll
        for (int ns = 0; ns < 4; ++ns) {
            int n = n0 + ns * 16 + lm;
            if (n >= VV) continue;
            float bb = bias[n];
#pragma unroll
            for (int r2 = 0; r2 < 4; ++r2) {
                int mrow = m0 + v * 128 + ms * 16 + quad * 4 + r2;
                if (mrow < 1584)
                    out[(size_t)(mrow & 15) * (TD * (size_t)VV) + (size_t)(mrow >> 4) * VV + n] =
                        acc[ms][ns][r2] + bb;
            }
        }
}

// ---------------- row softmax over V=50000, in place on d_out ----------------
__global__ __launch_bounds__(256) void k_softmax(float* __restrict__ out) {
    float* row = out + (size_t)blockIdx.x * VV;
    int tid = threadIdx.x;
    float m = -1e30f, s = 0.f;
    for (int i = tid; i < VV; i += 256) {
        float x = row[i];
        if (x > m) {
            s = s * expf(m - x) + 1.f;
            m = x;
        } else {
            s += expf(x - m);
        }
    }
    __shared__ float rm[256], rs[256];
    rm[tid] = m;
    rs[tid] = s;
    __syncthreads();
    for (int st = 128; st > 0; st >>= 1) {
        if (tid < st) {
            float m2 = rm[tid + st], s2 = rs[tid + st];
            float M = fmaxf(rm[tid], m2);
            rs[tid] = rs[tid] * expf(rm[tid] - M) + s2 * expf(m2 - M);
            rm[tid] = M;
        }
        __syncthreads();
    }
    float Mf = rm[0], inv = 1.f / rs[0];
    for (int i = tid; i < VV; i += 256) row[i] = expf(row[i] - Mf) * inv;
}

__global__ void k_covout(float* __restrict__ out, const float* __restrict__ cvl) {
    out[(size_t)BB * TD * VV] = cvl[0];
}

extern "C" void kernel_launch(void* const* d_in, const int* in_sizes, int n_in,
                              void* d_out, int out_size, void* d_ws, size_t ws_size,
                              hipStream_t stream) {
    const int* inputs = (const int*)d_in[0];
    const int* target = (const int*)d_in[1];
    const float* embed = (const float*)d_in[2];
    const float* Wih_f = (const float*)d_in[3];
    const float* Whh_f = (const float*)d_in[4];
    const float* b_f = (const float*)d_in[5];
    const float* Wih_b = (const float*)d_in[6];
    const float* Whh_b = (const float*)d_in[7];
    const float* b_b = (const float*)d_in[8];
    const float* Wih_d = (const float*)d_in[9];
    const float* Whh_d = (const float*)d_in[10];
    const float* b_d = (const float*)d_in[11];
    const float* Wh_w = (const float*)d_in[12];
    const float* Wh_b = (const float*)d_in[13];
    const float* Ws_w = (const float*)d_in[14];
    const float* Ws_b = (const float*)d_in[15];
    const float* Wc_w = (const float*)d_in[16];
    const float* Wc_b = (const float*)d_in[17];
    const float* v_w = (const float*)d_in[18];
    const float* v_b = (const float*)d_in[19];
    const float* V1_w = (const float*)d_in[20];
    const float* V1_b = (const float*)d_in[21];
    const float* V2_w = (const float*)d_in[22];
    const float* V2_b = (const float*)d_in[23];
    float* out = (float*)d_out;
    float* wsf = (float*)d_ws;

    float* Xf = wsf + OFF_XF;
    float* Xb = wsf + OFF_XB;
    float* Xd = wsf + OFF_XD;
    float* enc = wsf + OFF_ENC;
    float* cat = wsf + OFF_CAT;
    ushort_t* zbf = (ushort_t*)(wsf + OFF_ZBF);
    __half* attn_g = (__half*)(wsf + OFF_ATTN);
    __half* encT = (__half*)(wsf + OFF_XF);  // aliases Xf (dead after encoder)
    float* vWh = wsf + OFF_VWH;
    float* vWs = wsf + OFF_VWS;
    float* vWc = wsf + OFF_VWC;
    float* vWhw = wsf + OFF_VWHW;
    float* c0 = wsf + OFF_C0;
    ushort_t* henc = (ushort_t*)(wsf + OFF_HENC);
    ushort_t* hdec = (ushort_t*)(wsf + OFF_HDEC);
    float* p_pub = wsf + OFF_PPUB;
    float* q_pub = wsf + OFF_QPUB;
    unsigned* cnts = (unsigned*)(wsf + OFF_CNT);
    float* cvl = wsf + OFF_CVL;

    dim3 blk(256);
    k_init<<<32, 256, 0, stream>>>(wsf + OFF_HENC, (int)ZERO_N);
    k_precomp<<<1, 256, 0, stream>>>(v_w, Ws_w, Wc_w, Wh_w, Wh_b, Ws_b, Wc_b, v_b, vWs, vWc,
                                     vWhw, c0);
    k_xproj<<<dim3(16, 100), blk, 0, stream>>>(embed, inputs, LL, Wih_f, b_f, Xf, 6400);
    k_xproj<<<dim3(16, 100), blk, 0, stream>>>(embed, inputs, LL, Wih_b, b_b, Xb, 6400);
    k_xproj<<<dim3(16, 25), blk, 0, stream>>>(embed, target, 100, Wih_d, b_d, Xd, 1584);
    k_enc_pers<<<32, blk, 0, stream>>>(Xf, Xb, Whh_f, Whh_b, henc, cnts, enc);
    k_vwh<<<25, 256, 0, stream>>>(enc, vWhw, vWh);
    k_transpose<<<dim3(7, 8, 16), blk, 0, stream>>>(enc, encT);
    k_dec_pers<<<16, blk, 0, stream>>>(Xd, Whh_d, hdec, cnts + 32, vWh, vWs, vWc, c0, p_pub,
                                       q_pub, cat, attn_g, cvl);
    k_ctx_gemm<<<dim3(8, 16), blk, 0, stream>>>(attn_g, encT, cat);
    k_gemm_v1<<<dim3(12, 25), blk, 0, stream>>>(cat, V1_w, V1_b, zbf);
    k_gemm_v2<<<dim3(782, 4), blk, 0, stream>>>(zbf, V2_w, V2_b, out);
    k_softmax<<<1584, 256, 0, stream>>>(out);
    k_covout<<<1, 1, 0, stream>>>(out, cvl);
}

// Round 5
// 2575.826 us; speedup vs baseline: 1.5725x; 1.1874x over previous
//
#include <hip/hip_runtime.h>
#include <hip/hip_bf16.h>
#include <hip/hip_fp16.h>

// BiLSTM encoder (L=400) + coverage-attention LSTM decoder (T-1=99) + V=50000 softmax.
// B=16, E=128, H=256, 4H=1024, 2H=512, 3H=768.
//
// Round-7 = round-6 resubmission (round-4 bench failed on GPU acquisition,
// kernel never ran):
//  - Conflict-free h-exchange layout: producers store h directly in "phys"
//    order phys(m,k) = (k>>5)*1024B + ((k>>3)&3)*256B + m*16B + (k&7)*2B per
//    8KB plane. Staging is IDENTITY (linear 16B global->LDS), every MFMA
//    fragment read is a contiguous 1KB per wave -> SQ_LDS_BANK_CONFLICT ~0.
//  - XCD-local DATA path only: grid=128, active WGs bx%8 in {0,1}; runtime
//    XCC_ID uniformity check; if each group sits on one XCD, h/p/q exchange
//    uses sc0 (L2 coherence point, ~200cy) else sc0 sc1 (IC). Correct either
//    way (Guideline 16).
//  - Grid barrier ALWAYS uses the round-1/2-proven protocol (agent-scope
//    atomic add + sc0 sc1 poll): a wrong fast-path decision can only cause
//    stale data (absmax-detectable), never a deadlock.
//  - Counted waits: x-prefetch before VMCNT(4) (cc loads oldest); decoder
//    attention p/q loads then cc prefetch with vmcnt(5)/(4).
//  - Clamped prefetch indices (round-5 had UB negative row at t=399).

#define BB 16
#define LL 400
#define TD 99
#define G4 1024
#define H2 512
#define H3 768
#define VV 50000

typedef __attribute__((ext_vector_type(8))) short bf16x8_t;
typedef __attribute__((ext_vector_type(8))) _Float16 f16x8_t;
typedef __attribute__((ext_vector_type(4))) float f32x4_t;
typedef __attribute__((ext_vector_type(4))) unsigned int u32x4_t;
typedef unsigned short ushort_t;

static constexpr size_t OFF_XF   = 0;            // 6,553,600  (aliased by encT f16 after encoder)
static constexpr size_t OFF_XB   = 6553600;      // 6,553,600
static constexpr size_t OFF_XD   = 13107200;     // 1,622,016
static constexpr size_t OFF_ENC  = 14729216;     // 3,276,800
static constexpr size_t OFF_CAT  = 18006016;     // 1,216,512
static constexpr size_t OFF_ZBF  = 19222528;     // 786,432 floats = ushort[2048*768]
static constexpr size_t OFF_ATTN = 20008960;     // 372,736 floats = half[16*112*416]
static constexpr size_t OFF_VWH  = 20381696;     // 6400
static constexpr size_t OFF_VWS  = 20388096;     // 256
static constexpr size_t OFF_VWC  = 20388352;     // 512
static constexpr size_t OFF_VWHW = 20388864;     // 512
static constexpr size_t OFF_C0   = 20389376;     // 16
static constexpr size_t OFF_HENC = 20389392;     // ushort[2][2][2][4096] (dir, par, plane)
static constexpr size_t OFF_HDEC = 20405776;     // ushort[2][2][4096]
static constexpr size_t OFF_PPUB = 20413968;     // 512
static constexpr size_t OFF_QPUB = 20414480;     // 32
static constexpr size_t OFF_CNT  = 20414512;     // 288 u32: counters @128B-spaced slots + xcc arrays
static constexpr size_t OFF_CVL  = 20414800;     // 16
static constexpr size_t OFF_END  = 20414816;
static constexpr size_t ZERO_N   = OFF_END - OFF_HENC;  // 25,424

__device__ __forceinline__ ushort_t f2bf(float x) {
    unsigned u = __float_as_uint(x);
    unsigned r = u + 0x7FFFu + ((u >> 16) & 1u);
    return (ushort_t)(r >> 16);
}
__device__ __forceinline__ float bf2f(ushort_t h) {
    return __uint_as_float(((unsigned)h) << 16);
}
__device__ __forceinline__ float wred_sum(float v) {
#pragma unroll
    for (int o = 32; o; o >>= 1) v += __shfl_xor(v, o);
    return v;
}
__device__ __forceinline__ float wred_max(float v) {
#pragma unroll
    for (int o = 32; o; o >>= 1) v = fmaxf(v, __shfl_xor(v, o));
    return v;
}
__device__ __forceinline__ float sigf(float x) { return 1.f / (1.f + expf(-x)); }

#define SB0() __builtin_amdgcn_sched_barrier(0)
#define VMCNT(n) asm volatile("s_waitcnt vmcnt(" #n ")" ::: "memory")

#define GLD4(d0, d1, d2, d3, a0, a1, a2, a3, FL)                                   \
    asm volatile("global_load_dwordx4 %0, %4, off " FL "\n\t"                      \
                 "global_load_dwordx4 %1, %5, off " FL "\n\t"                      \
                 "global_load_dwordx4 %2, %6, off " FL "\n\t"                      \
                 "global_load_dwordx4 %3, %7, off " FL                             \
                 : "=&v"(d0), "=&v"(d1), "=&v"(d2), "=&v"(d3)                      \
                 : "v"(a0), "v"(a1), "v"(a2), "v"(a3) : "memory")

#define GLD1(d, a, FL)                                                             \
    asm volatile("global_load_dword %0, %1, off " FL : "=&v"(d) : "v"(a) : "memory")

#define GST_SHORT2(p, vhi, vlo, FL)                                                \
    asm volatile("global_store_short %0, %2, off " FL "\n\t"                       \
                 "global_store_short %1, %3, off " FL                              \
                 :: "v"(p), "v"((p) + 4096), "v"(vhi), "v"(vlo) : "memory")

#define GST1(p, v, FL)                                                             \
    asm volatile("global_store_dword %0, %1, off " FL :: "v"(p), "v"(v) : "memory")

// tid==0 only. PROVEN protocol (rounds 1-2): agent-scope add, sc0 sc1 poll.
#define GRID_BAR(cntp, tgt)                                                        \
    do {                                                                           \
        __hip_atomic_fetch_add(cntp, 1u, __ATOMIC_RELAXED, __HIP_MEMORY_SCOPE_AGENT); \
        unsigned _v;                                                               \
        for (;;) {                                                                 \
            asm volatile("global_load_dword %0, %1, off sc0 sc1\n\t"               \
                         "s_waitcnt vmcnt(0)"                                      \
                         : "=v"(_v) : "v"(cntp) : "memory");                       \
            if (_v >= (tgt)) break;                                                \
            __builtin_amdgcn_s_sleep(1);                                           \
        }                                                                          \
    } while (0)

// ---------------- init: zero state region ----------------
__global__ void k_init(float* __restrict__ p, int n) {
    for (int i = blockIdx.x * blockDim.x + threadIdx.x; i < n; i += gridDim.x * blockDim.x)
        p[i] = 0.0f;
}

// ---------------- precompute v-folded attention vectors ----------------
__global__ void k_precomp(const float* __restrict__ v, const float* __restrict__ Ws_w,
                          const float* __restrict__ Wc_w, const float* __restrict__ Wh_w,
                          const float* __restrict__ Wh_b, const float* __restrict__ Ws_b,
                          const float* __restrict__ Wc_b, const float* __restrict__ v_b,
                          float* __restrict__ vWs, float* __restrict__ vWc,
                          float* __restrict__ vWhw, float* __restrict__ c0) {
    int tid = threadIdx.x;
    {
        float a = 0.f;
        for (int j = 0; j < 256; ++j) a += v[j] * Ws_w[j * 256 + tid];
        vWs[tid] = a;
    }
    for (int k = tid; k < 400; k += 256) {
        float a = 0.f;
        for (int j = 0; j < 256; ++j) a += v[j] * Wc_w[j * 400 + k];
        vWc[k] = a;
    }
    for (int k = tid; k < 512; k += 256) {
        float a = 0.f;
        for (int j = 0; j < 256; ++j) a += v[j] * Wh_w[j * 512 + k];
        vWhw[k] = a;
    }
    if (tid == 0) {
        float a = 0.f;
        for (int j = 0; j < 256; ++j) a += v[j] * (Wh_b[j] + Ws_b[j] + Wc_b[j]);
        c0[0] = a + v_b[0];
    }
}

// ---------------- gather x-projection GEMM (split-bf16, 3 MFMA) ----------------
__global__ __launch_bounds__(256) void k_xproj(
    const float* __restrict__ emb, const int* __restrict__ toks, int tokStride,
    const float* __restrict__ Wih, const float* __restrict__ bias,
    float* __restrict__ C, int M) {
    __shared__ __attribute__((aligned(16))) ushort_t Ah[64 * 32], Al[64 * 32];
    __shared__ __attribute__((aligned(16))) ushort_t Bh[64 * 32], Bl[64 * 32];
    int tid = threadIdx.x;
    int m0 = blockIdx.y * 64, n0 = blockIdx.x * 64;
    int lrow = tid >> 2, lc = (tid & 3) * 8;
    int g = tid >> 6, lane = tid & 63, lm = lane & 15, quad = lane >> 4;
    f32x4_t acc[4];
#pragma unroll
    for (int i = 0; i < 4; ++i) acc[i] = (f32x4_t){0.f, 0.f, 0.f, 0.f};
    int mr = m0 + lrow;
    int l = mr >> 4, bb2 = mr & 15;
    int tok = (mr < M) ? toks[bb2 * tokStride + l] : 0;
    const float* arow = emb + (size_t)tok * 128;
    const float* brow = Wih + (size_t)(n0 + lrow) * 128;
    for (int k0 = 0; k0 < 128; k0 += 32) {
        float av[8], bv[8];
        *(float4*)(av) = *(const float4*)(arow + k0 + lc);
        *(float4*)(av + 4) = *(const float4*)(arow + k0 + lc + 4);
        *(float4*)(bv) = *(const float4*)(brow + k0 + lc);
        *(float4*)(bv + 4) = *(const float4*)(brow + k0 + lc + 4);
        __syncthreads();
#pragma unroll
        for (int j = 0; j < 8; ++j) {
            ushort_t h = f2bf(av[j]);
            Ah[lrow * 32 + lc + j] = h;
            Al[lrow * 32 + lc + j] = f2bf(av[j] - bf2f(h));
            ushort_t h2 = f2bf(bv[j]);
            Bh[lrow * 32 + lc + j] = h2;
            Bl[lrow * 32 + lc + j] = f2bf(bv[j] - bf2f(h2));
        }
        __syncthreads();
        bf16x8_t ah = *(const bf16x8_t*)(Ah + (g * 16 + lm) * 32 + quad * 8);
        bf16x8_t al = *(const bf16x8_t*)(Al + (g * 16 + lm) * 32 + quad * 8);
#pragma unroll
        for (int ns = 0; ns < 4; ++ns) {
            bf16x8_t bh = *(const bf16x8_t*)(Bh + (ns * 16 + lm) * 32 + quad * 8);
            bf16x8_t bl = *(const bf16x8_t*)(Bl + (ns * 16 + lm) * 32 + quad * 8);
            acc[ns] = __builtin_amdgcn_mfma_f32_16x16x32_bf16(ah, bh, acc[ns], 0, 0, 0);
            acc[ns] = __builtin_amdgcn_mfma_f32_16x16x32_bf16(ah, bl, acc[ns], 0, 0, 0);
            acc[ns] = __builtin_amdgcn_mfma_f32_16x16x32_bf16(al, bh, acc[ns], 0, 0, 0);
        }
    }
#pragma unroll
    for (int ns = 0; ns < 4; ++ns) {
        int n = n0 + ns * 16 + lm;
        float bb = bias[n];
#pragma unroll
        for (int r2 = 0; r2 < 4; ++r2) {
            int mm = m0 + g * 16 + quad * 4 + r2;
            if (mm < M) C[(size_t)mm * 1024 + n] = acc[ns][r2] + bb;
        }
    }
}

// ================= persistent encoder =================
// grid 128; active: (bx&7)<2 -> dir=(bx&7), w=bx>>3 (16 WGs/dir; one XCD per
// dir under de-facto round-robin, verified at runtime; FL is data-path only).
#define ENC_LOOP(FL)                                                               \
    for (int t = 0; t < 400; ++t) {                                                \
        int par = t & 1;                                                           \
        const char* sb = sA + (par << 14);                                         \
        GLD4(r0, r1, r2, r3, sb, sb + 4096, sb + 8192, sb + 12288, FL);            \
        SB0();                                                                     \
        {                                                                          \
            int ln = (t < 399) ? (dir ? (398 - t) : (t + 1)) : l0;                 \
            const float* Xr = X + (size_t)(ln * 16 + m) * 1024;                    \
            xn0 = Xr[k]; xn1 = Xr[256 + k]; xn2 = Xr[512 + k]; xn3 = Xr[768 + k];  \
        }                                                                          \
        SB0();                                                                     \
        VMCNT(4); /* cc loads are the 4 oldest */                                  \
        SB0();                                                                     \
        *(u32x4_t*)hxw = r0;                                                       \
        *(u32x4_t*)(hxw + 4096) = r1;                                              \
        *(u32x4_t*)(hxw + 8192) = r2;                                              \
        *(u32x4_t*)(hxw + 12288) = r3;                                             \
        __syncthreads();                                                           \
        f32x4_t a0 = (f32x4_t){0.f, 0.f, 0.f, 0.f}, a1 = a0, a2 = a0;              \
        _Pragma("unroll")                                                          \
        for (int kk = 0; kk < 8; ++kk) {                                           \
            bf16x8_t ah = *(const bf16x8_t*)(fha + kk * 1024);                     \
            bf16x8_t al = *(const bf16x8_t*)(fla + kk * 1024);                     \
            a0 = __builtin_amdgcn_mfma_f32_16x16x32_bf16(ah, Bh[kk], a0, 0, 0, 0); \
            a1 = __builtin_amdgcn_mfma_f32_16x16x32_bf16(ah, Bl[kk], a1, 0, 0, 0); \
            a2 = __builtin_amdgcn_mfma_f32_16x16x32_bf16(al, Bh[kk], a2, 0, 0, 0); \
        }                                                                          \
        f32x4_t acv = a0 + a1 + a2;                                                \
        _Pragma("unroll")                                                          \
        for (int ri = 0; ri < 4; ++ri)                                             \
            pre[g * 256 + (quad * 4 + ri) * 16 + lm] = acv[ri];                    \
        __syncthreads();                                                           \
        float gi = pre[tid] + x0;                                                  \
        float gf = pre[256 + tid] + x1;                                            \
        float gg = pre[512 + tid] + x2;                                            \
        float go = pre[768 + tid] + x3;                                            \
        int l = dir ? (399 - t) : t;                                               \
        c = sigf(gf) * c + sigf(gi) * tanhf(gg);                                   \
        float h = sigf(go) * tanhf(c);                                             \
        enc[((size_t)m * 400 + l) * 512 + dir * 256 + k] = h;                      \
        ushort_t hh = f2bf(h);                                                     \
        unsigned hhi32 = hh, hlo32 = f2bf(h - bf2f(hh));                           \
        ushort_t* so = par ? so1 : so0;                                            \
        GST_SHORT2(so, hhi32, hlo32, FL);                                          \
        VMCNT(0);                                                                  \
        SB0();                                                                     \
        x0 = xn0; x1 = xn1; x2 = xn2; x3 = xn3;                                    \
        __syncthreads();                                                           \
        if (tid == 0) GRID_BAR(cnt, (unsigned)(t + 1) * 16u);                      \
        __syncthreads();                                                           \
    }

__global__ __launch_bounds__(256) void k_enc_pers(
    const float* __restrict__ Xf, const float* __restrict__ Xb,
    const float* __restrict__ Whh_f, const float* __restrict__ Whh_b,
    ushort_t* __restrict__ hbuf, unsigned* __restrict__ gsync, float* __restrict__ enc) {
    __shared__ float pre[1024];
    __shared__ __attribute__((aligned(16))) char hx[16384];
    __shared__ int s_uni;
    int bx = blockIdx.x;
    int r8 = bx & 7;
    if (r8 >= 2) return;
    int dir = r8;
    int w = bx >> 3;
    const float* Whh = dir ? Whh_b : Whh_f;
    const float* X = dir ? Xb : Xf;
    unsigned* cnt = gsync + dir * 32;
    unsigned* scnt = gsync + 96 + dir * 32;
    unsigned* xccs = gsync + 192 + dir * 32;
    ushort_t* hb = hbuf + dir * 16384;  // [par(8192)][plane(4096)] ushorts
    int tid = threadIdx.x;
    int g = tid >> 6, lane = tid & 63, lm = lane & 15, quad = lane >> 4;
    int gbase = 256 * g + 16 * w;
    bf16x8_t Bh[8], Bl[8];
    {
        const float* wr = Whh + (size_t)(gbase + lm) * 256;
#pragma unroll
        for (int kk = 0; kk < 8; ++kk) {
            union { bf16x8_t v; ushort_t u[8]; } hh, ll;
#pragma unroll
            for (int j = 0; j < 8; ++j) {
                float x = wr[kk * 32 + quad * 8 + j];
                ushort_t hi = f2bf(x);
                hh.u[j] = hi;
                ll.u[j] = f2bf(x - bf2f(hi));
            }
            Bh[kk] = hh.v;
            Bl[kk] = ll.v;
        }
    }
    int m = tid >> 4;
    int k = w * 16 + (tid & 15);
    // phys h-exchange layout (ushort idx within plane):
    int p_idx = ((k >> 5) << 9) + (((k >> 3) & 3) << 7) + (m << 3) + (k & 7);
    ushort_t* so0 = hb + 8192 + p_idx;  // par=0 writes buf1
    ushort_t* so1 = hb + p_idx;         // par=1 writes buf0
    const char* sA = (const char*)hb + (size_t)tid * 16;  // identity staging src
    char* hxw = hx + tid * 16;
    const char* fha = hx + quad * 256 + lm * 16;
    const char* fla = fha + 8192;
    // ---- XCD-uniformity check ----
    unsigned myxcc;
    asm volatile("s_getreg_b32 %0, hwreg(HW_REG_XCC_ID)" : "=s"(myxcc));
    if (tid == 0) {
        s_uni = 1;
        asm volatile("global_store_dword %0, %1, off sc0 sc1\n\ts_waitcnt vmcnt(0)"
                     :: "v"(xccs + w), "v"(myxcc) : "memory");
        __hip_atomic_fetch_add(scnt, 1u, __ATOMIC_RELAXED, __HIP_MEMORY_SCOPE_AGENT);
        while (__hip_atomic_load(scnt, __ATOMIC_RELAXED, __HIP_MEMORY_SCOPE_AGENT) < 16u)
            __builtin_amdgcn_s_sleep(8);
    }
    __syncthreads();
    if (tid < 16) {
        unsigned o;
        asm volatile("global_load_dword %0, %1, off sc0 sc1\n\ts_waitcnt vmcnt(0)"
                     : "=v"(o) : "v"(xccs + tid) : "memory");
        if (o != myxcc) s_uni = 0;
    }
    __syncthreads();
    bool fast = (s_uni != 0);
    // ---- recurrence ----
    float c = 0.f;
    int l0 = dir ? 399 : 0;
    const float* Xr0 = X + (size_t)(l0 * 16 + m) * 1024;
    float x0 = Xr0[k], x1 = Xr0[256 + k], x2 = Xr0[512 + k], x3 = Xr0[768 + k];
    float xn0 = 0.f, xn1 = 0.f, xn2 = 0.f, xn3 = 0.f;
    u32x4_t r0, r1, r2, r3;
    if (fast) {
        ENC_LOOP("sc0")
    } else {
        ENC_LOOP("sc0 sc1")
    }
}

// ---------------- vWh[b*L+l] = vWhw . enc[b,l,:] ----------------
__global__ void k_vwh(const float* __restrict__ enc, const float* __restrict__ vWhw,
                      float* __restrict__ vWh) {
    int rr = blockIdx.x * 256 + threadIdx.x;
    const float* row = enc + (size_t)rr * H2;
    float acc = 0.f;
#pragma unroll 4
    for (int k = 0; k < H2; k += 4) {
        float4 e = *(const float4*)(row + k);
        float4 wv = *(const float4*)(vWhw + k);
        acc += e.x * wv.x + e.y * wv.y + e.z * wv.z + e.w * wv.w;
    }
    vWh[rr] = acc;
}

// ---------------- transpose enc -> encT f16 [b][j][l(416, zero-padded)] ----------------
__global__ __launch_bounds__(256) void k_transpose(const float* __restrict__ enc,
                                                   __half* __restrict__ encT) {
    __shared__ float tb[64][65];
    int lt = blockIdx.x, jt = blockIdx.y, b = blockIdx.z;
    int l0 = lt * 64, j0 = jt * 64;
    int tid = threadIdx.x;
    for (int i = tid; i < 4096; i += 256) {
        int li = i >> 6, jj = i & 63;
        int l = l0 + li;
        tb[jj][li] = (l < 400) ? enc[((size_t)b * 400 + l) * 512 + j0 + jj] : 0.f;
    }
    __syncthreads();
    for (int i = tid; i < 4096; i += 256) {
        int jj = i >> 6, li = i & 63;
        int l = l0 + li;
        if (l < 416) encT[((size_t)b * 512 + j0 + jj) * 416 + l] = __float2half(tb[jj][li]);
    }
}

// ================= persistent decoder =================
// grid 128; active: (bx&7)==0, w=b=bx>>3 (16 WGs; one XCD under de-facto map).
#define DEC_RUN(FL)                                                                \
    {                                                                              \
        GLD4(r0, r1, r2, r3, sA, sA + 4096, sA + 8192, sA + 12288, FL);            \
        for (int t = 0; t < TD; ++t) {                                             \
            int par = t & 1;                                                       \
            {                                                                      \
                int tn = (t + 1 < TD) ? (t + 1) : 0;                               \
                const float* Xr = Xd + (size_t)(tn * 16 + m) * 1024;               \
                xn0 = Xr[k]; xn1 = Xr[256 + k]; xn2 = Xr[512 + k]; xn3 = Xr[768 + k]; \
            }                                                                      \
            SB0();                                                                 \
            VMCNT(4); /* cc loads (issued last iter / prologue) are oldest */      \
            SB0();                                                                 \
            *(u32x4_t*)hxw = r0;                                                   \
            *(u32x4_t*)(hxw + 4096) = r1;                                          \
            *(u32x4_t*)(hxw + 8192) = r2;                                          \
            *(u32x4_t*)(hxw + 12288) = r3;                                         \
            float qv = wc1 * covL[tid];                                            \
            if (has2) qv += wc2 * covL[tid + 256];                                 \
            qv = wred_sum(qv);                                                     \
            __syncthreads();                                                       \
            f32x4_t a0 = (f32x4_t){0.f, 0.f, 0.f, 0.f}, a1 = a0, a2 = a0;          \
            _Pragma("unroll")                                                      \
            for (int kk = 0; kk < 8; ++kk) {                                       \
                bf16x8_t ah = *(const bf16x8_t*)(fha + kk * 1024);                 \
                bf16x8_t al = *(const bf16x8_t*)(fla + kk * 1024);                 \
                a0 = __builtin_amdgcn_mfma_f32_16x16x32_bf16(ah, Bh[kk], a0, 0, 0, 0); \
                a1 = __builtin_amdgcn_mfma_f32_16x16x32_bf16(ah, Bl[kk], a1, 0, 0, 0); \
                a2 = __builtin_amdgcn_mfma_f32_16x16x32_bf16(al, Bh[kk], a2, 0, 0, 0); \
            }                                                                      \
            f32x4_t acv = a0 + a1 + a2;                                            \
            _Pragma("unroll")                                                      \
            for (int ri = 0; ri < 4; ++ri)                                         \
                pre[g * 256 + (quad * 4 + ri) * 16 + lm] = acv[ri];                \
            if (lane == 0) rr[g] = qv;                                             \
            __syncthreads();                                                       \
            float gi = pre[tid] + x0;                                              \
            float gf = pre[256 + tid] + x1;                                        \
            float gg = pre[512 + tid] + x2;                                        \
            float go = pre[768 + tid] + x3;                                        \
            c = sigf(gf) * c + sigf(gi) * tanhf(gg);                               \
            float h = sigf(go) * tanhf(c);                                         \
            cat[((size_t)t * 16 + m) * 768 + k] = h;                               \
            ushort_t hh = f2bf(h);                                                 \
            unsigned hhi32 = hh, hlo32 = f2bf(h - bf2f(hh));                       \
            ushort_t* so = par ? so1 : so0;                                        \
            GST_SHORT2(so, hhi32, hlo32, FL);                                      \
            psh[tid] = vwsk * h;                                                   \
            if (tid == 0) {                                                        \
                float qs = rr[0] + rr[1] + rr[2] + rr[3];                          \
                GST1(q_pub + par * 16 + b, qs, FL);                                \
            }                                                                      \
            __syncthreads();                                                       \
            if (tid < 16) {                                                        \
                float s = 0.f;                                                     \
                _Pragma("unroll")                                                  \
                for (int j = 0; j < 16; ++j) s += psh[tid * 16 + j];               \
                GST1(p_pub + par * 256 + w * 16 + tid, s, FL);                     \
            }                                                                      \
            VMCNT(0);                                                              \
            SB0();                                                                 \
            x0 = xn0; x1 = xn1; x2 = xn2; x3 = xn3;                                \
            __syncthreads();                                                       \
            if (tid == 0) GRID_BAR(cnt, (unsigned)(t + 1) * 16u);                  \
            __syncthreads();                                                       \
            /* attention: issue p,q loads FIRST, then next-step cc loads */        \
            float pld, qld;                                                        \
            GLD1(pld, p_pub + par * 256 + tid, FL);                                \
            GLD1(qld, q_pub + par * 16 + (tid & 15), FL);                          \
            if (t < TD - 1) {                                                      \
                const char* sb = sA + ((1 - par) << 14);                           \
                GLD4(r0, r1, r2, r3, sb, sb + 4096, sb + 8192, sb + 12288, FL);    \
                VMCNT(5);                                                          \
            } else {                                                               \
                VMCNT(1);                                                          \
            }                                                                      \
            SB0();                                                                 \
            vred[tid] = pld;                                                       \
            __syncthreads();                                                       \
            if (tid < 128) vred[tid] += vred[tid + 128];                           \
            __syncthreads();                                                       \
            if (tid < 64) vred[tid] += vred[tid + 64];                             \
            __syncthreads();                                                       \
            if (tid < 32) vred[tid] += vred[tid + 32];                             \
            __syncthreads();                                                       \
            if (t < TD - 1) { VMCNT(4); } else { VMCNT(0); }                       \
            SB0();                                                                 \
            if (tid < 16) vswcS[tid] = vred[tid] + vred[tid + 16] + qld;           \
            __syncthreads();                                                       \
            float vs = vswcS[tid & 15] + c0v;                                      \
            float lg1 = vh1 + vs;                                                  \
            float lg2 = has2 ? (vh2 + vs) : -1e30f;                                \
            float mx = wred_max(fmaxf(lg1, lg2));                                  \
            if (lane == 0) rr[g] = mx;                                             \
            __syncthreads();                                                       \
            float M = fmaxf(fmaxf(rr[0], rr[1]), fmaxf(rr[2], rr[3]));             \
            float e1 = expf(lg1 - M);                                              \
            float e2 = has2 ? expf(lg2 - M) : 0.f;                                 \
            float sv = wred_sum(e1 + e2);                                          \
            if (lane == 0) rr[4 + g] = sv;                                         \
            __syncthreads();                                                       \
            float inv = 1.f / (rr[4] + rr[5] + rr[6] + rr[7]);                     \
            float a1v = e1 * inv, a2v = e2 * inv;                                  \
            float cv1 = covL[tid];                                                 \
            float cl = fminf(a1v, cv1);                                            \
            covL[tid] = cv1 + a1v;                                                 \
            __half* arow = attn_g + ((size_t)b * 112 + t) * 416;                   \
            arow[tid] = __float2half(a1v);                                         \
            if (has2) {                                                            \
                float cv2 = covL[tid + 256];                                       \
                cl += fminf(a2v, cv2);                                             \
                covL[tid + 256] = cv2 + a2v;                                       \
                arow[256 + tid] = __float2half(a2v);                               \
            }                                                                      \
            cl = wred_sum(cl);                                                     \
            __syncthreads();                                                       \
            if (lane == 0) rr[g] = cl;                                             \
            __syncthreads();                                                       \
            if (tid == 0) cl_acc += rr[0] + rr[1] + rr[2] + rr[3];                 \
            __syncthreads();                                                       \
        }                                                                          \
    }

__global__ __launch_bounds__(256) void k_dec_pers(
    const float* __restrict__ Xd, const float* __restrict__ Whh_d,
    ushort_t* __restrict__ hbuf, unsigned* __restrict__ gsync,
    const float* __restrict__ vWh, const float* __restrict__ vWs,
    const float* __restrict__ vWc, const float* __restrict__ c0g,
    float* __restrict__ p_pub, float* __restrict__ q_pub, float* __restrict__ cat,
    __half* __restrict__ attn_g, float* __restrict__ cvl) {
    __shared__ float pre[1024];
    __shared__ float covL[400];
    __shared__ float vred[256];
    __shared__ float psh[256];
    __shared__ float vswcS[16];
    __shared__ float rr[8];
    __shared__ __attribute__((aligned(16))) char hx[16384];
    __shared__ int s_uni;
    int bx = blockIdx.x;
    if ((bx & 7) != 0) return;
    int w = bx >> 3;
    int b = w;
    unsigned* cnt = gsync + 64;
    unsigned* scnt = gsync + 160;
    unsigned* xccs = gsync + 256;
    int tid = threadIdx.x;
    int g = tid >> 6, lane = tid & 63, lm = lane & 15, quad = lane >> 4;
    int gbase = 256 * g + 16 * w;
    bf16x8_t Bh[8], Bl[8];
    {
        const float* wr = Whh_d + (size_t)(gbase + lm) * 256;
#pragma unroll
        for (int kk = 0; kk < 8; ++kk) {
            union { bf16x8_t v; ushort_t u[8]; } hh, ll;
#pragma unroll
            for (int j = 0; j < 8; ++j) {
                float x = wr[kk * 32 + quad * 8 + j];
                ushort_t hi = f2bf(x);
                hh.u[j] = hi;
                ll.u[j] = f2bf(x - bf2f(hi));
            }
            Bh[kk] = hh.v;
            Bl[kk] = ll.v;
        }
    }
    int m = tid >> 4;
    int k = w * 16 + (tid & 15);
    int p_idx = ((k >> 5) << 9) + (((k >> 3) & 3) << 7) + (m << 3) + (k & 7);
    ushort_t* so0 = hbuf + 8192 + p_idx;
    ushort_t* so1 = hbuf + p_idx;
    const char* sA = (const char*)hbuf + (size_t)tid * 16;
    char* hxw = hx + tid * 16;
    const char* fha = hx + quad * 256 + lm * 16;
    const char* fla = fha + 8192;
    // ---- XCD-uniformity check ----
    unsigned myxcc;
    asm volatile("s_getreg_b32 %0, hwreg(HW_REG_XCC_ID)" : "=s"(myxcc));
    if (tid == 0) {
        s_uni = 1;
        asm volatile("global_store_dword %0, %1, off sc0 sc1\n\ts_waitcnt vmcnt(0)"
                     :: "v"(xccs + w), "v"(myxcc) : "memory");
        __hip_atomic_fetch_add(scnt, 1u, __ATOMIC_RELAXED, __HIP_MEMORY_SCOPE_AGENT);
        while (__hip_atomic_load(scnt, __ATOMIC_RELAXED, __HIP_MEMORY_SCOPE_AGENT) < 16u)
            __builtin_amdgcn_s_sleep(8);
    }
    __syncthreads();
    if (tid < 16) {
        unsigned o;
        asm volatile("global_load_dword %0, %1, off sc0 sc1\n\ts_waitcnt vmcnt(0)"
                     : "=v"(o) : "v"(xccs + tid) : "memory");
        if (o != myxcc) s_uni = 0;
    }
    __syncthreads();
    bool fast = (s_uni != 0);
    // ---- hoisted loop-invariants ----
    float c = 0.f, cl_acc = 0.f;
    for (int i = tid; i < 400; i += 256) covL[i] = 0.f;
    bool has2 = tid < 144;
    float c0v = c0g[0];
    float vwsk = vWs[k];
    float wc1 = vWc[tid];
    float wc2 = has2 ? vWc[tid + 256] : 0.f;
    float vh1 = vWh[b * 400 + tid];
    float vh2 = has2 ? vWh[b * 400 + 256 + tid] : 0.f;
    const float* Xr0 = Xd + (size_t)m * 1024;
    float x0 = Xr0[k], x1 = Xr0[256 + k], x2 = Xr0[512 + k], x3 = Xr0[768 + k];
    float xn0 = 0.f, xn1 = 0.f, xn2 = 0.f, xn3 = 0.f;
    u32x4_t r0, r1, r2, r3;
    __syncthreads();
    if (fast) {
        DEC_RUN("sc0")
    } else {
        DEC_RUN("sc0 sc1")
    }
    if (tid == 0) atomicAdd(cvl, cl_acc);
}

// ---------------- batched context GEMM: cat[t*16+b][256:768] = attn @ enc ----------------
__global__ __launch_bounds__(256) void k_ctx_gemm(const __half* __restrict__ attn_g,
                                                  const __half* __restrict__ encT,
                                                  float* __restrict__ cat) {
    int jt = blockIdx.x, b = blockIdx.y;
    int tid = threadIdx.x, v = tid >> 6, lane = tid & 63, lm = lane & 15, quad = lane >> 4;
    f32x4_t acc[7];
#pragma unroll
    for (int i = 0; i < 7; ++i) acc[i] = (f32x4_t){0.f, 0.f, 0.f, 0.f};
    int j = jt * 64 + v * 16 + lm;
    const _Float16* brow = (const _Float16*)(encT + ((size_t)b * 512 + j) * 416);
    const _Float16* abase = (const _Float16*)(attn_g + (size_t)b * 112 * 416);
    for (int k0 = 0; k0 < 416; k0 += 32) {
        f16x8_t bf = *(const f16x8_t*)(brow + k0 + quad * 8);
#pragma unroll
        for (int mt = 0; mt < 7; ++mt) {
            f16x8_t af = *(const f16x8_t*)(abase + (size_t)(mt * 16 + lm) * 416 + k0 + quad * 8);
            acc[mt] = __builtin_amdgcn_mfma_f32_16x16x32_f16(af, bf, acc[mt], 0, 0, 0);
        }
    }
#pragma unroll
    for (int mt = 0; mt < 7; ++mt)
#pragma unroll
        for (int r2 = 0; r2 < 4; ++r2) {
            int t = mt * 16 + quad * 4 + r2;
            if (t < 99) cat[((size_t)t * 16 + b) * 768 + 256 + j] = acc[mt][r2];
        }
}

// ---------------- V1 GEMM: zbf[2048,768] = bf16(cat @ V1.T + b) ----------------
__global__ __launch_bounds__(256) void k_gemm_v1(const float* __restrict__ A,
                                                 const float* __restrict__ Bw,
                                                 const float* __restrict__ bias,
                                                 ushort_t* __restrict__ Cbf) {
    __shared__ __attribute__((aligned(16))) ushort_t As[64 * 32], Bs[64 * 32];
    int tid = threadIdx.x;
    int m0 = blockIdx.y * 64, n0 = blockIdx.x * 64;
    int lrow = tid >> 2, lc = (tid & 3) * 8;
    int g = tid >> 6, lane = tid & 63, lm = lane & 15, quad = lane >> 4;
    f32x4_t acc[4];
#pragma unroll
    for (int i = 0; i < 4; ++i) acc[i] = (f32x4_t){0.f, 0.f, 0.f, 0.f};
    const float* ap0 = A + (size_t)(m0 + lrow) * 768;
    const float* bp0 = Bw + (size_t)(n0 + lrow) * 768;
    for (int k0 = 0; k0 < 768; k0 += 32) {
        float av[8], bv[8];
        *(float4*)av = *(const float4*)(ap0 + k0 + lc);
        *(float4*)(av + 4) = *(const float4*)(ap0 + k0 + lc + 4);
        *(float4*)bv = *(const float4*)(bp0 + k0 + lc);
        *(float4*)(bv + 4) = *(const float4*)(bp0 + k0 + lc + 4);
        __syncthreads();
#pragma unroll
        for (int jj = 0; jj < 8; ++jj) {
            As[lrow * 32 + lc + jj] = f2bf(av[jj]);
            Bs[lrow * 32 + lc + jj] = f2bf(bv[jj]);
        }
        __syncthreads();
        bf16x8_t ah = *(const bf16x8_t*)(As + (g * 16 + lm) * 32 + quad * 8);
#pragma unroll
        for (int ns = 0; ns < 4; ++ns) {
            bf16x8_t bh = *(const bf16x8_t*)(Bs + (ns * 16 + lm) * 32 + quad * 8);
            acc[ns] = __builtin_amdgcn_mfma_f32_16x16x32_bf16(ah, bh, acc[ns], 0, 0, 0);
        }
    }
#pragma unroll
    for (int ns = 0; ns < 4; ++ns) {
        int n = n0 + ns * 16 + lm;
        float bb = bias[n];
#pragma unroll
        for (int r2 = 0; r2 < 4; ++r2) {
            int mm = m0 + g * 16 + quad * 4 + r2;
            Cbf[(size_t)mm * 768 + n] = f2bf(acc[ns][r2] + bb);
        }
    }
}

// ---------------- V2 GEMM: out[b][t][n] = softmax-input logits (bf16 MFMA) ----------------
__global__ __launch_bounds__(256) void k_gemm_v2(const ushort_t* __restrict__ Abf,
                                                 const float* __restrict__ V2w,
                                                 const float* __restrict__ bias,
                                                 float* __restrict__ out) {
    __shared__ __attribute__((aligned(16))) ushort_t As[512 * 32];
    __shared__ __attribute__((aligned(16))) ushort_t Bs[64 * 32];
    int tid = threadIdx.x;
    int n0 = blockIdx.x * 64;
    int m0 = blockIdx.y * 512;
    int v = tid >> 6, lane = tid & 63, lm = lane & 15, quad = lane >> 4;
    int lrow = tid >> 2, lc = (tid & 3) * 8;
    f32x4_t acc[8][4];
#pragma unroll
    for (int i = 0; i < 8; ++i)
#pragma unroll
        for (int jn = 0; jn < 4; ++jn) acc[i][jn] = (f32x4_t){0.f, 0.f, 0.f, 0.f};
    int nr = n0 + lrow;
    for (int k0 = 0; k0 < 768; k0 += 32) {
        __syncthreads();
#pragma unroll
        for (int i = 0; i < 8; ++i) {
            int row = i * 64 + lrow;
            *(uint4*)(As + row * 32 + lc) =
                *(const uint4*)(Abf + (size_t)(m0 + row) * 768 + k0 + lc);
        }
        {
            float bv8[8];
            if (nr < VV) {
                const float* bp = V2w + (size_t)nr * 768 + k0 + lc;
                *(float4*)bv8 = *(const float4*)bp;
                *(float4*)(bv8 + 4) = *(const float4*)(bp + 4);
            } else {
#pragma unroll
                for (int jj = 0; jj < 8; ++jj) bv8[jj] = 0.f;
            }
#pragma unroll
            for (int jj = 0; jj < 8; ++jj) Bs[lrow * 32 + lc + jj] = f2bf(bv8[jj]);
        }
        __syncthreads();
        bf16x8_t bn[4];
#pragma unroll
        for (int ns = 0; ns < 4; ++ns)
            bn[ns] = *(const bf16x8_t*)(Bs + (ns * 16 + lm) * 32 + quad * 8);
#pragma unroll
        for (int ms = 0; ms < 8; ++ms) {
            bf16x8_t ah = *(const bf16x8_t*)(As + (v * 128 + ms * 16 + lm) * 32 + quad * 8);
#pragma unroll
            for (int ns = 0; ns < 4; ++ns)
                acc[ms][ns] = __builtin_amdgcn_mfma_f32_16x16x32_bf16(ah, bn[ns], acc[ms][ns], 0, 0, 0);
        }
    }
#pragma unroll
    for (int ms = 0; ms < 8; ++ms)
#pragma unroll
        for (int ns = 0; ns < 4; ++ns) {
            int n = n0 + ns * 16 + lm;
            if (n >= VV) continue;
            float bb = bias[n];
#pragma unroll
            for (int r2 = 0; r2 < 4; ++r2) {
                int mrow = m0 + v * 128 + ms * 16 + quad * 4 + r2;
                if (mrow < 1584)
                    out[(size_t)(mrow & 15) * (TD * (size_t)VV) + (size_t)(mrow >> 4) * VV + n] =
                        acc[ms][ns][r2] + bb;
            }
        }
}

// ---------------- row softmax over V=50000, in place on d_out ----------------
__global__ __launch_bounds__(256) void k_softmax(float* __restrict__ out) {
    float* row = out + (size_t)blockIdx.x * VV;
    int tid = threadIdx.x;
    float m = -1e30f, s = 0.f;
    for (int i = tid; i < VV; i += 256) {
        float x = row[i];
        if (x > m) {
            s = s * expf(m - x) + 1.f;
            m = x;
        } else {
            s += expf(x - m);
        }
    }
    __shared__ float rm[256], rs[256];
    rm[tid] = m;
    rs[tid] = s;
    __syncthreads();
    for (int st = 128; st > 0; st >>= 1) {
        if (tid < st) {
            float m2 = rm[tid + st], s2 = rs[tid + st];
            float M = fmaxf(rm[tid], m2);
            rs[tid] = rs[tid] * expf(rm[tid] - M) + s2 * expf(m2 - M);
            rm[tid] = M;
        }
        __syncthreads();
    }
    float Mf = rm[0], inv = 1.f / rs[0];
    for (int i = tid; i < VV; i += 256) row[i] = expf(row[i] - Mf) * inv;
}

__global__ void k_covout(float* __restrict__ out, const float* __restrict__ cvl) {
    out[(size_t)BB * TD * VV] = cvl[0];
}

extern "C" void kernel_launch(void* const* d_in, const int* in_sizes, int n_in,
                              void* d_out, int out_size, void* d_ws, size_t ws_size,
                              hipStream_t stream) {
    const int* inputs = (const int*)d_in[0];
    const int* target = (const int*)d_in[1];
    const float* embed = (const float*)d_in[2];
    const float* Wih_f = (const float*)d_in[3];
    const float* Whh_f = (const float*)d_in[4];
    const float* b_f = (const float*)d_in[5];
    const float* Wih_b = (const float*)d_in[6];
    const float* Whh_b = (const float*)d_in[7];
    const float* b_b = (const float*)d_in[8];
    const float* Wih_d = (const float*)d_in[9];
    const float* Whh_d = (const float*)d_in[10];
    const float* b_d = (const float*)d_in[11];
    const float* Wh_w = (const float*)d_in[12];
    const float* Wh_b = (const float*)d_in[13];
    const float* Ws_w = (const float*)d_in[14];
    const float* Ws_b = (const float*)d_in[15];
    const float* Wc_w = (const float*)d_in[16];
    const float* Wc_b = (const float*)d_in[17];
    const float* v_w = (const float*)d_in[18];
    const float* v_b = (const float*)d_in[19];
    const float* V1_w = (const float*)d_in[20];
    const float* V1_b = (const float*)d_in[21];
    const float* V2_w = (const float*)d_in[22];
    const float* V2_b = (const float*)d_in[23];
    float* out = (float*)d_out;
    float* wsf = (float*)d_ws;

    float* Xf = wsf + OFF_XF;
    float* Xb = wsf + OFF_XB;
    float* Xd = wsf + OFF_XD;
    float* enc = wsf + OFF_ENC;
    float* cat = wsf + OFF_CAT;
    ushort_t* zbf = (ushort_t*)(wsf + OFF_ZBF);
    __half* attn_g = (__half*)(wsf + OFF_ATTN);
    __half* encT = (__half*)(wsf + OFF_XF);  // aliases Xf (dead after encoder)
    float* vWh = wsf + OFF_VWH;
    float* vWs = wsf + OFF_VWS;
    float* vWc = wsf + OFF_VWC;
    float* vWhw = wsf + OFF_VWHW;
    float* c0 = wsf + OFF_C0;
    ushort_t* henc = (ushort_t*)(wsf + OFF_HENC);
    ushort_t* hdec = (ushort_t*)(wsf + OFF_HDEC);
    float* p_pub = wsf + OFF_PPUB;
    float* q_pub = wsf + OFF_QPUB;
    unsigned* cnts = (unsigned*)(wsf + OFF_CNT);
    float* cvl = wsf + OFF_CVL;

    dim3 blk(256);
    k_init<<<32, 256, 0, stream>>>(wsf + OFF_HENC, (int)ZERO_N);
    k_precomp<<<1, 256, 0, stream>>>(v_w, Ws_w, Wc_w, Wh_w, Wh_b, Ws_b, Wc_b, v_b, vWs, vWc,
                                     vWhw, c0);
    k_xproj<<<dim3(16, 100), blk, 0, stream>>>(embed, inputs, LL, Wih_f, b_f, Xf, 6400);
    k_xproj<<<dim3(16, 100), blk, 0, stream>>>(embed, inputs, LL, Wih_b, b_b, Xb, 6400);
    k_xproj<<<dim3(16, 25), blk, 0, stream>>>(embed, target, 100, Wih_d, b_d, Xd, 1584);
    k_enc_pers<<<128, blk, 0, stream>>>(Xf, Xb, Whh_f, Whh_b, henc, cnts, enc);
    k_vwh<<<25, 256, 0, stream>>>(enc, vWhw, vWh);
    k_transpose<<<dim3(7, 8, 16), blk, 0, stream>>>(enc, encT);
    k_dec_pers<<<128, blk, 0, stream>>>(Xd, Whh_d, hdec, cnts, vWh, vWs, vWc, c0, p_pub,
                                        q_pub, cat, attn_g, cvl);
    k_ctx_gemm<<<dim3(8, 16), blk, 0, stream>>>(attn_g, encT, cat);
    k_gemm_v1<<<dim3(12, 25), blk, 0, stream>>>(cat, V1_w, V1_b, zbf);
    k_gemm_v2<<<dim3(782, 4), blk, 0, stream>>>(zbf, V2_w, V2_b, out);
    k_softmax<<<1584, 256, 0, stream>>>(out);
    k_covout<<<1, 1, 0, stream>>>(out, cvl);
}